// Round 9
// baseline (292.273 us; speedup 1.0000x reference)
//
#include <hip/hip_runtime.h>
#include <math.h>

#define NPT 32768
#define NH 8
#define HD 24
#define EDIM 28
#define NHASH 3
#define NSEG 48
#define NRH 24   // N_HASHES * NUM_HEADS = 24 alpha rows

typedef unsigned long long u64;
typedef unsigned short ushort;
typedef __attribute__((__vector_size__(8 * sizeof(short)))) short bf16x8;
typedef __attribute__((__vector_size__(4 * sizeof(float)))) float floatx4;
typedef __attribute__((__vector_size__(4 * sizeof(unsigned int)))) unsigned int uint32x4;

__device__ __forceinline__ ushort f2bf(float f) {
    unsigned u = __float_as_uint(f);
    unsigned r = u + 0x7FFF + ((u >> 16) & 1);
    return (ushort)(r >> 16);
}
__device__ __forceinline__ float us2f(ushort u) {
    return __uint_as_float(((unsigned)u) << 16);
}

// ---------------- K0b: RPE weights + folded score matrices (fp64) ----------------
__global__ __launch_bounds__(256) void k0b(
    const float* __restrict__ wrpe, const float* __restrict__ Wq,
    const float* __restrict__ Wk, const float* __restrict__ alphas,
    double* __restrict__ w64, double* __restrict__ cqp64,
    double* __restrict__ Aq, double* __restrict__ Ak, double* __restrict__ ct) {
    __shared__ double sw[16], sc[16];
    int t = threadIdx.x;
    if (t < 16) {
        int h = t >> 1, c = t & 1;
        double s = 0.0;
        for (int i = 0; i < 24; i++)
            for (int j = 0; j < 8; j++)
                s += (double)wrpe[(h * 24 + i) * 16 + c * 8 + j];
        double m = s / 192.0;
        sw[t] = m * m;
        sc[t] = sqrt(2.0) * fabs(m);
        w64[t] = sw[t];
        cqp64[t] = sc[t];
    }
    __syncthreads();
    const double QSCALE = 1.0 / sqrt(24.0);
    for (int idx = t; idx < 24 * NRH; idx += 256) {
        int i = idx / NRH, rh = idx % NRH;
        int h = rh & 7;
        double aq = 0.0, ak = 0.0;
        for (int e = 0; e < 24; e++) {
            double al = (double)alphas[rh * 28 + e];
            aq += (double)Wq[i * 192 + h * 24 + e] * al;
            ak += (double)Wk[i * 192 + h * 24 + e] * al;
        }
        Aq[idx] = aq * QSCALE;
        Ak[idx] = ak;
    }
    if (t < NRH) {
        int h = t & 7;
        ct[t * 4 + 0] = (double)alphas[t * 28 + 24] * sc[h * 2 + 0];
        ct[t * 4 + 1] = (double)alphas[t * 28 + 25] * sc[h * 2 + 1];
        ct[t * 4 + 2] = (double)alphas[t * 28 + 26];
        ct[t * 4 + 3] = (double)alphas[t * 28 + 27];
    }
}

// ---------------- K2s: fused fp64 LN + hash scores + xnf emit ----------------
__global__ __launch_bounds__(512) void k2s(
    const float* __restrict__ x, const float* __restrict__ n1g,
    const float* __restrict__ n1b, const float* __restrict__ coords,
    const double* __restrict__ Aq, const double* __restrict__ Ak,
    const double* __restrict__ ct, const double* __restrict__ w64,
    u64* __restrict__ keys, float* __restrict__ xnf) {
    __shared__ double sA[2][24][NRH];
    __shared__ double sCt[NRH][4];
    __shared__ double sW64[16];
    __shared__ double sGB[48];
    __shared__ double sXn[8][24];
    int t = threadIdx.x;
    for (int i = t; i < 24 * NRH; i += 512) sA[0][i / NRH][i % NRH] = Aq[i];
    for (int i = t; i < 24 * NRH; i += 512) sA[1][i / NRH][i % NRH] = Ak[i];
    for (int i = t; i < NRH * 4; i += 512) sCt[i / 4][i % 4] = ct[i];
    if (t < 16) sW64[t] = w64[t];
    if (t < 24) { sGB[t] = (double)n1g[t]; sGB[24 + t] = (double)n1b[t]; }
    __syncthreads();
    int wv = t >> 6, l = t & 63;
    for (int g = 0; g < 8; g++) {
        int n = blockIdx.x * 64 + g * 8 + wv;
        double xv = (l < 24) ? (double)x[(u64)n * 24 + l] : 0.0;
        double s = xv;
        s += __shfl_xor(s, 1); s += __shfl_xor(s, 2); s += __shfl_xor(s, 4);
        s += __shfl_xor(s, 8); s += __shfl_xor(s, 16);
        double mu = s / 24.0;
        double d = (l < 24) ? (xv - mu) : 0.0;
        double v2 = d * d;
        v2 += __shfl_xor(v2, 1); v2 += __shfl_xor(v2, 2); v2 += __shfl_xor(v2, 4);
        v2 += __shfl_xor(v2, 8); v2 += __shfl_xor(v2, 16);
        double rstd = 1.0 / sqrt(v2 / 24.0 + 1e-5);
        if (l < 24) {
            double xn = d * rstd * sGB[l] + sGB[24 + l];
            sXn[wv][l] = xn;
            xnf[(u64)n * 24 + l] = (float)xn;
        }
        // no barrier: sXn[wv] written and read by the same wave only
        double p0 = (double)coords[(u64)n * 3 + 1];
        double p1 = (double)coords[(u64)n * 3 + 2];
        if (l < 2 * NRH) {
            int qk = l / NRH, rh = l % NRH;
            int h = rh & 7;
            double sqn = sW64[2 * h] * p0 * p0 + sW64[2 * h + 1] * p1 * p1;
            double acc = sCt[rh][0] * p0 + sCt[rh][1] * p1;
            acc += qk ? (sCt[rh][2] - sqn * sCt[rh][3]) : (sCt[rh][3] - sqn * sCt[rh][2]);
            for (int i = 0; i < 24; i++) acc += sXn[wv][i] * sA[qk][i][rh];
            u64 u = (u64)__double_as_longlong(acc);
            if (u >> 63) u = ~u; else u |= 0x8000000000000000ULL;
            u64 key = (u & ~(u64)32767) | (u64)n;
            keys[(u64)l * NPT + n] = key;  // segment = qk*24 + rh = l
        }
    }
}

// ---------------- Bitonic sort helpers ----------------
__device__ __forceinline__ u64 shflx64(u64 v, int d) {
    int lo = __shfl_xor((int)(unsigned)v, d);
    int hi = __shfl_xor((int)(unsigned)(v >> 32), d);
    return ((u64)(unsigned)hi << 32) | (unsigned)lo;
}
__device__ __forceinline__ void cswap(u64& a, u64& b, bool up) {
    if ((a > b) == up) { u64 tmp = a; a = b; b = tmp; }
}
__device__ __forceinline__ u64* sslot(u64* s, int i) {
    int a = i << 3;
    a ^= ((a >> 9) & 7) << 4;
    return (u64*)((char*)s + a);
}
__device__ __forceinline__ void reg_passes(u64 e[8], int ib, int K, int jmax) {
    for (int j = jmax; j >= 1; j >>= 1) {
#pragma unroll
        for (int k = 0; k < 8; k++)
            if ((k & j) == 0) cswap(e[k], e[k | j], ((ib + k) & K) == 0);
    }
}
__device__ __forceinline__ void shfl_passes(u64 e[8], int t, int segoff, int K, int jhi, int jlo) {
    for (int j = jhi; j >= jlo; j >>= 1) {
        int d = j >> 3;
        bool lower = (t & d) == 0;
        bool up = ((segoff + ((t & ~d) << 3)) & K) == 0;
        bool keepmin = (lower == up);
#pragma unroll
        for (int k = 0; k < 8; k++) {
            u64 o = shflx64(e[k], d);
            bool ownsm = e[k] < o;
            e[k] = (ownsm == keepmin) ? e[k] : o;
        }
    }
}

// ---------------- Fused K2p + sort_local_full ----------------
// blockIdx < 192: full bitonic sort of one 8192-key chunk (unchanged logic).
// blockIdx >= 192: k2p projections for 32 points (depends only on k2s's xnf,
// NOT on the sort) -> fills the CU/wave slots the 192-block sort leaves idle.
// Shared memory is a 64 KB union (sort: u64[8192]; k2p: 48 KB ushort tile).
// q-hat is pre-scaled by 1/ln2 so k3 uses native exp2.
#define K2P_PTS 32
#define INVLN2F 1.4426950408889634f
__global__ __launch_bounds__(1024) void k2p_sort(
    u64* keys,
    const float* __restrict__ xnf,
    const float* __restrict__ Wq, const float* __restrict__ Wk,
    const float* __restrict__ Wv, const float* __restrict__ coords,
    const double* __restrict__ w64, const double* __restrict__ cqp64,
    ushort* __restrict__ qhatB, ushort* __restrict__ khatB, ushort* __restrict__ varrB) {
    __shared__ __align__(16) char smem[65536];
    int t = threadIdx.x;
    if (blockIdx.x < 192) {
        // ---------- sort_local_full path ----------
        u64* s = (u64*)smem;
        u64 gbase = (u64)blockIdx.x * 8192;
        int segoff = (int)(gbase & 32767);
        int ib = segoff + t * 8;
        u64 e[8];
#pragma unroll
        for (int k = 0; k < 8; k++) e[k] = keys[gbase + t * 8 + k];
        reg_passes(e, ib, 2, 1);
        reg_passes(e, ib, 4, 2);
        reg_passes(e, ib, 8, 4);
        for (int K = 16; K <= 512; K <<= 1) {
            shfl_passes(e, t, segoff, K, K >> 1, 8);
            reg_passes(e, ib, K, 4);
        }
#pragma unroll
        for (int k = 0; k < 8; k++) *sslot(s, t * 8 + k) = e[k];
        __syncthreads();
        for (int K = 1024; K <= 8192; K <<= 1) {
            for (int j = K >> 1; j >= 512; j >>= 1) {
                for (int p = t; p < 4096; p += 1024) {
                    int i = ((p & ~(j - 1)) << 1) | (p & (j - 1));
                    int i2 = i | j;
                    bool up = (((segoff + i) & K) == 0);
                    u64 a = *sslot(s, i), b = *sslot(s, i2);
                    if ((a > b) == up) { *sslot(s, i) = b; *sslot(s, i2) = a; }
                }
                __syncthreads();
            }
#pragma unroll
            for (int k = 0; k < 8; k++) e[k] = *sslot(s, t * 8 + k);
            shfl_passes(e, t, segoff, K, 256, 8);
            reg_passes(e, ib, K, 4);
            if (K < 8192) {
#pragma unroll
                for (int k = 0; k < 8; k++) *sslot(s, t * 8 + k) = e[k];
                __syncthreads();
            } else {
#pragma unroll
                for (int k = 0; k < 8; k++) keys[gbase + t * 8 + k] = e[k];
            }
        }
    } else {
        // ---------- k2p path ----------
        ushort* sT = (ushort*)smem;   // [arr][h][pt][e] 49152 B
        int n0 = (blockIdx.x - 192) * K2P_PTS;
        if (t < 576) {
            int m = t / 192, jj = t % 192;
            const float* W = (m == 0) ? Wq : ((m == 1) ? Wk : Wv);
            float wc[24];
#pragma unroll
            for (int i = 0; i < 24; i++) wc[i] = W[i * 192 + jj];
            const float scale = (m == 0) ? (float)(1.4426950408889634 / sqrt(24.0)) : 1.0f;
            int h = jj / 24, e = jj % 24;
            ushort* sbase = sT + ((m * 8 + h) * K2P_PTS) * 32 + e;
            for (int p = 0; p < K2P_PTS; p++) {
                int n = n0 + p;
                const float* xr = xnf + (u64)n * 24;   // wave-uniform -> s_load
                float acc = 0.f;
#pragma unroll
                for (int i = 0; i < 24; i++) acc += xr[i] * wc[i];
                sbase[p * 32] = f2bf(acc * scale);
            }
        } else if (t < 640) {
            int l = t - 576;
            int h2 = l >> 3, e2 = 24 + (l & 7);
            double c0 = cqp64[h2 * 2], c1 = cqp64[h2 * 2 + 1];
            double wa = w64[h2 * 2], wb = w64[h2 * 2 + 1];
            ushort* qb = sT + ((0 * 8 + h2) * K2P_PTS) * 32 + e2;
            ushort* kb = sT + ((1 * 8 + h2) * K2P_PTS) * 32 + e2;
            ushort* vb = sT + ((2 * 8 + h2) * K2P_PTS) * 32 + e2;
            for (int p = 0; p < K2P_PTS; p++) {
                int n = n0 + p;
                double p0 = (double)coords[(u64)n * 3 + 1];
                double p1 = (double)coords[(u64)n * 3 + 2];
                float qv, kv;
                if (e2 < 26) {
                    int c = e2 - 24;
                    float qp = (float)((c ? c1 : c0) * (c ? p1 : p0));
                    qv = qp; kv = qp;
                } else if (e2 < 28) {
                    double sqn = wa * p0 * p0 + wb * p1 * p1;
                    if (e2 == 26) { qv = (float)(-sqn); kv = 1.0f; }
                    else          { qv = 1.0f; kv = (float)(-sqn); }
                } else {
                    qv = 0.0f; kv = 0.0f;
                }
                qb[p * 32] = f2bf(qv * INVLN2F);   // q-side 1/ln2 prescale
                kb[p * 32] = f2bf(kv);
                vb[p * 32] = 0;   // init pad cols of varr slab (copied out; not read)
            }
        }
        __syncthreads();
        // coalesced copy-out: 24 slabs x 128 16B-chunks = 3072.
        for (int c = t; c < 3 * 8 * K2P_PTS * 4; c += 1024) {
            int arrh = c >> 7, off = c & 127;
            int arr = arrh >> 3, hh = arrh & 7;
            uint32x4 v = *(const uint32x4*)(sT + arrh * (K2P_PTS * 32) + off * 8);
            ushort* op = (arr == 0) ? qhatB : ((arr == 1) ? khatB : varrB);
            *(uint32x4*)(op + (u64)hh * NPT * 32 + (u64)n0 * 32 + off * 8) = v;
        }
    }
}

// tail1 fused with the K=16384 j=8192 global pass: load own chunk + partner,
// keep min/max per element (keepmin for chunk-in-segment 0,3; max for 1,2),
// then run the K=16384 merge j=4096..1 (full sort of the 8192-chunk's role).
// After this kernel: segment first 16384 fully ASCENDING, second 16384 DESCENDING.
__global__ __launch_bounds__(1024) void sort_tail1_fused(u64* keys) {
    __shared__ u64 s[8192];
    int t = threadIdx.x;
    u64 gbase = (u64)blockIdx.x * 8192;
    u64 pbase = gbase ^ 8192ULL;          // partner chunk at distance j=8192
    int ci = (int)((gbase >> 13) & 3);    // chunk index within 32768-segment
    bool keepmin = (ci == 0) || (ci == 3);
    int segoff = (int)(gbase & 32767);
    int ib = segoff + t * 8;
    for (int i = t; i < 8192; i += 1024) {
        u64 a = keys[gbase + i];
        u64 b = keys[pbase + i];
        u64 mn = a < b ? a : b;
        u64 mx = a < b ? b : a;
        *sslot(s, i) = keepmin ? mn : mx;
    }
    __syncthreads();
    const int K = 16384;
    for (int j = 4096; j >= 512; j >>= 1) {
        for (int p = t; p < 4096; p += 1024) {
            int i = ((p & ~(j - 1)) << 1) | (p & (j - 1));
            int i2 = i | j;
            bool up = (((segoff + i) & K) == 0);
            u64 a = *sslot(s, i), b = *sslot(s, i2);
            if ((a > b) == up) { *sslot(s, i) = b; *sslot(s, i2) = a; }
        }
        __syncthreads();
    }
    u64 e[8];
#pragma unroll
    for (int k = 0; k < 8; k++) e[k] = *sslot(s, t * 8 + k);
    shfl_passes(e, t, segoff, K, 256, 8);
    reg_passes(e, ib, K, 4);
#pragma unroll
    for (int k = 0; k < 8; k++) keys[gbase + t * 8 + k] = e[k];
}

// ---------------- sort_corank: replaces sort_global2 + sort_local_tail ----------------
// Each segment after tail1 = run A (16384 asc) ++ run B (16384 desc).
// k3 consumes 128-key blocks as SETS (order within block irrelevant; that is
// why old local_tail stopped at minj=128). The rank-128 partition of the
// merged segment is found by merge-path co-rank: for rank r, the unique a with
// A[a-1] < B'[r-a] and B'[r-a-1] < A[a]  (B'[i] = B[16383-i], ascending;
// keys are distinct since low 15 bits hold the index). One block per output
// 128-set: wave0/wave1 compute the two boundary co-ranks, then gather slices.
__device__ __forceinline__ int corank(int r, const u64* __restrict__ A,
                                      const u64* __restrict__ B) {
    int lo = r - 16384; if (lo < 0) lo = 0;
    int hi = r < 16384 ? r : 16384;
    while (lo < hi) {
        int a = (lo + hi + 1) >> 1;          // a >= 1 in-loop
        int b = r - a;                        // 0 <= b < 16384 in-loop
        u64 Bv = B[16383 - b];                // B'[b]
        if (A[a - 1] < Bv) lo = a; else hi = a - 1;
    }
    return lo;
}
__global__ __launch_bounds__(128) void sort_corank(const u64* __restrict__ keys,
                                                   u64* __restrict__ keys2) {
    __shared__ int sh[2];
    int seg = blockIdx.x >> 8;        // 48 segments
    int g = blockIdx.x & 255;         // 256 output blocks/segment
    const u64* A = keys + (u64)seg * 32768;
    const u64* B = A + 16384;
    int t = threadIdx.x;
    int r0 = g * 128;
    if (t == 0)  sh[0] = corank(r0, A, B);
    if (t == 64) sh[1] = corank(r0 + 128, A, B);
    __syncthreads();
    int aLo = sh[0], aHi = sh[1];
    int na = aHi - aLo;
    int bLo = r0 - aLo;
    u64 v;
    if (t < na) v = A[aLo + t];
    else        v = B[16383 - (bLo + (t - na))];
    keys2[(u64)seg * 32768 + r0 + t] = v;
}

// ---------------- K3: block attention via bf16 MFMA ----------------
// v8 = round-5 passing v2 structure (separate khatB/varrB, per-wave K
// gathers, 4 blocks/CU) + exp2f softmax (q prescaled by 1/ln2 in k2p),
// z = m*ln2 + log(s). Reads keys2 (co-rank partitioned sets).
__global__ __launch_bounds__(256, 4) void k3_attn(
    const u64* __restrict__ keys, const ushort* __restrict__ qhatB,
    const ushort* __restrict__ khatB, const ushort* __restrict__ varrB,
    ushort* __restrict__ ozB) {
    int rh3 = blockIdx.x % 24;
    int b = blockIdx.x / 24;
    int h = rh3 & 7, r = rh3 >> 3;
    __shared__ __align__(16) char smem[6144 + 32768 + 512];
    char* sVt = smem;                       // 24 rows x 256 B (phi-permuted, swizzled)
    char* sP  = smem + 6144;                // 128 rows x 256 B (phi-permuted, swizzled)
    ushort* qidx = (ushort*)(smem + 6144 + 32768);
    ushort* kidx = qidx + 128;
    int t = threadIdx.x;
    int segQ = r * 8 + h, segK = 24 + r * 8 + h;
    if (t < 128) {
        qidx[t] = (ushort)(keys[(u64)segQ * NPT + b * 128 + t] & 32767ULL);
    } else {
        int i = t - 128;
        kidx[i] = (ushort)(keys[(u64)segK * NPT + b * 128 + i] & 32767ULL);
    }
    __syncthreads();

    int wave = t >> 6, L = t & 63;
    int quad = L >> 4, n16 = L & 15;

    const bf16x8* Qg = (const bf16x8*)(qhatB + (u64)h * NPT * 32);
    const bf16x8* Kg = (const bf16x8*)(khatB + (u64)h * NPT * 32);
    bf16x8 afr[2];
#pragma unroll
    for (int rtg = 0; rtg < 2; rtg++) {
        int qi = qidx[wave * 32 + rtg * 16 + n16];
        afr[rtg] = Qg[(u64)qi * 4 + quad];
    }
    bf16x8 bfr[8];
#pragma unroll
    for (int ct = 0; ct < 8; ct++) {
        int ki = kidx[ct * 16 + n16];
        bfr[ct] = Kg[(u64)ki * 4 + quad];
    }
    // stage V^T into phi-permuted + swizzled layout: key t -> byte col
    // phi(t)*2 = ((t&15)<<4)|((t>>4)<<1); per-row XOR (e&7)<<4.
    if (t < 128) {
        int ki = kidx[t];
        const bf16x8* vr = (const bf16x8*)(varrB + ((u64)h * NPT + ki) * 32);
        bf16x8 v0 = vr[0], v1 = vr[1], v2 = vr[2];
        int colb = ((t & 15) << 4) | ((t >> 4) << 1);
#pragma unroll
        for (int e = 0; e < 8; e++) {
            int e0 = e, e1 = 8 + e, e2 = 16 + e;
            *(short*)(sVt + e0 * 256 + (colb ^ ((e0 & 7) << 4))) = v0[e];
            *(short*)(sVt + e1 * 256 + (colb ^ ((e1 & 7) << 4))) = v1[e];
            *(short*)(sVt + e2 * 256 + (colb ^ ((e2 & 7) << 4))) = v2[e];
        }
    }
    __syncthreads();

    floatx4 acc[2][8];
#pragma unroll
    for (int rtg = 0; rtg < 2; rtg++)
#pragma unroll
        for (int ct = 0; ct < 8; ct++)
            acc[rtg][ct] = (floatx4){0.f, 0.f, 0.f, 0.f};
#pragma unroll
    for (int ct = 0; ct < 8; ct++) {
#pragma unroll
        for (int rtg = 0; rtg < 2; rtg++)
            acc[rtg][ct] = __builtin_amdgcn_mfma_f32_16x16x32_bf16(afr[rtg], bfr[ct], acc[rtg][ct], 0, 0, 0);
    }

    // Softmax (scores in log2 units; exp2f = native v_exp_f32).
    float mrow[2][4], srow[2][4];
#pragma unroll
    for (int rtg = 0; rtg < 2; rtg++) {
#pragma unroll
        for (int rg = 0; rg < 4; rg++) {
            float m = acc[rtg][0][rg];
#pragma unroll
            for (int ct = 1; ct < 8; ct++) m = fmaxf(m, acc[rtg][ct][rg]);
            m = fmaxf(m, __shfl_xor(m, 1));
            m = fmaxf(m, __shfl_xor(m, 2));
            m = fmaxf(m, __shfl_xor(m, 4));
            m = fmaxf(m, __shfl_xor(m, 8));
            mrow[rtg][rg] = m;
            float p[8];
            float s = 0.0f;
#pragma unroll
            for (int ct = 0; ct < 8; ct++) {
                p[ct] = exp2f(acc[rtg][ct][rg] - m);
                s += p[ct];
            }
            s += __shfl_xor(s, 1);
            s += __shfl_xor(s, 2);
            s += __shfl_xor(s, 4);
            s += __shfl_xor(s, 8);
            srow[rtg][rg] = s;
            unsigned w0, w1, w2, w3;
            asm("v_cvt_pk_bf16_f32 %0, %1, %2" : "=v"(w0) : "v"(p[0]), "v"(p[1]));
            asm("v_cvt_pk_bf16_f32 %0, %1, %2" : "=v"(w1) : "v"(p[2]), "v"(p[3]));
            asm("v_cvt_pk_bf16_f32 %0, %1, %2" : "=v"(w2) : "v"(p[4]), "v"(p[5]));
            asm("v_cvt_pk_bf16_f32 %0, %1, %2" : "=v"(w3) : "v"(p[6]), "v"(p[7]));
            int row = wave * 32 + rtg * 16 + quad * 4 + rg;
            uint32x4 pk = {w0, w1, w2, w3};
            *(uint32x4*)(sP + row * 256 + (((n16 << 4)) ^ ((row & 7) << 4))) = pk;
        }
    }
    // sP written and read by the same wave only -> no barrier needed.

    floatx4 occ[2][2];
#pragma unroll
    for (int rtg = 0; rtg < 2; rtg++)
#pragma unroll
        for (int ct2 = 0; ct2 < 2; ct2++)
            occ[rtg][ct2] = (floatx4){0.f, 0.f, 0.f, 0.f};
#pragma unroll
    for (int ks = 0; ks < 4; ks++) {
        int kb = ks * 64 + quad * 16;   // byte offset of this lane's 8 phys cols
        bf16x8 bv[2], av[2];
#pragma unroll
        for (int ct2 = 0; ct2 < 2; ct2++) {
            int e = ct2 * 16 + n16;
            int ec = (e < 24) ? e : 0;  // cols 24..31 discarded; clamp keeps reads in sVt
            bv[ct2] = *(const bf16x8*)(sVt + ec * 256 + (kb ^ ((ec & 7) << 4)));
        }
#pragma unroll
        for (int rtg = 0; rtg < 2; rtg++) {
            int rowA = wave * 32 + rtg * 16 + n16;
            av[rtg] = *(const bf16x8*)(sP + rowA * 256 + (kb ^ ((rowA & 7) << 4)));
        }
#pragma unroll
        for (int rtg = 0; rtg < 2; rtg++)
#pragma unroll
            for (int ct2 = 0; ct2 < 2; ct2++)
                occ[rtg][ct2] = __builtin_amdgcn_mfma_f32_16x16x32_bf16(av[rtg], bv[ct2], occ[rtg][ct2], 0, 0, 0);
    }

    const float LN2F = 0.6931471805599453f;
#pragma unroll
    for (int rtg = 0; rtg < 2; rtg++) {
#pragma unroll
        for (int rg = 0; rg < 4; rg++) {
            int row = wave * 32 + rtg * 16 + quad * 4 + rg;
            int oi = qidx[row];
            float inv = 1.0f / srow[rtg][rg];
            ushort* orow = ozB + ((u64)segQ * NPT + oi) * 32;
#pragma unroll
            for (int ct2 = 0; ct2 < 2; ct2++) {
                int col = ct2 * 16 + n16;
                if (col < 24) orow[col] = f2bf(occ[rtg][ct2][rg] * inv);
            }
            if (n16 == 0)
                *(float*)(orow + 24) = mrow[rtg][rg] * LN2F + __logf(srow[rtg][rg]);
        }
    }
}

// ---------------- K4: hash combine + Wo + residual + LN2 + FFN (fp32, 32 pts/block) ----------------
#define K4PTS 32
#define AT_STR 196   // floats; 16B-aligned rows
#define W_STR 28     // transposed small-matrix row stride (16B-aligned)
__global__ __launch_bounds__(256) void k4_final(
    const ushort* __restrict__ ozB,
    const float* __restrict__ x,
    const float* __restrict__ Wo, const float* __restrict__ bo,
    const float* __restrict__ g2, const float* __restrict__ b2,
    const float* __restrict__ W1, const float* __restrict__ b1f,
    const float* __restrict__ W2, const float* __restrict__ b2f,
    float* __restrict__ out) {
    __shared__ __align__(16) float sWoT[24][AT_STR];
    __shared__ __align__(16) float sW1T[24][W_STR], sW2T[24][W_STR];
    __shared__ float sB[5 * 24];
    __shared__ __align__(16) float attn[K4PTS][AT_STR];
    __shared__ float xrow[K4PTS][25];
    __shared__ __align__(16) float h2row[K4PTS][W_STR];
    __shared__ __align__(16) float ffrow[K4PTS][W_STR];
    int t = threadIdx.x;
    int base = blockIdx.x * K4PTS;
    for (int i = t; i < 4608; i += 256) sWoT[i % 24][i / 24] = Wo[i];
    for (int i = t; i < 576; i += 256) {
        sW1T[i % 24][i / 24] = W1[i];   // sW1T[out][in]
        sW2T[i % 24][i / 24] = W2[i];
    }
    if (t < 24) {
        sB[t] = bo[t]; sB[24 + t] = g2[t]; sB[48 + t] = b2[t];
        sB[72 + t] = b1f[t]; sB[96 + t] = b2f[t];
    }
    // zero the pad columns so float4 reads over 24..27 are benign
    if (t < K4PTS * 4) {
        int p = t >> 2, c = 24 + (t & 3);
        h2row[p][c] = 0.f; ffrow[p][c] = 0.f;
    }
    if (t < 24 * 4) {
        int rr = t >> 2, c = 24 + (t & 3);
        sW1T[rr][c] = 0.f; sW2T[rr][c] = 0.f;
    }
    {
        int p = t >> 3, h = t & 7;
        int n = base + p;
        const ushort* r0 = ozB + ((u64)(0 * 8 + h) * NPT + n) * 32;
        const ushort* r1 = ozB + ((u64)(1 * 8 + h) * NPT + n) * 32;
        const ushort* r2 = ozB + ((u64)(2 * 8 + h) * NPT + n) * 32;
        float z0 = *(const float*)(r0 + 24);
        float z1 = *(const float*)(r1 + 24);
        float z2 = *(const float*)(r2 + 24);
        float zm = fmaxf(z0, fmaxf(z1, z2));
        float e0 = __expf(z0 - zm), e1 = __expf(z1 - zm), e2 = __expf(z2 - zm);
        float inv = 1.0f / (e0 + e1 + e2);
        float w0 = e0 * inv, w1 = e1 * inv, w2 = e2 * inv;
#pragma unroll
        for (int e = 0; e < 24; e++)
            attn[p][h * 24 + e] = w0 * us2f(r0[e]) + w1 * us2f(r1[e]) + w2 * us2f(r2[e]);
    }
    __syncthreads();
    int p = t >> 3, oe = t & 7;
    int n = base + p;
    {
        const floatx4* ap = (const floatx4*)&attn[p][0];
        const floatx4* w0p = (const floatx4*)&sWoT[oe][0];
        const floatx4* w1p = (const floatx4*)&sWoT[oe + 8][0];
        const floatx4* w2p = (const floatx4*)&sWoT[oe + 16][0];
        floatx4 A0 = {0.f, 0.f, 0.f, 0.f}, A1 = A0, A2 = A0;
        for (int ii = 0; ii < 48; ii++) {
            floatx4 av = ap[ii];
            A0 += av * w0p[ii];
            A1 += av * w1p[ii];
            A2 += av * w2p[ii];
        }
        float a0 = A0[0] + A0[1] + A0[2] + A0[3];
        float a1 = A1[0] + A1[1] + A1[2] + A1[3];
        float a2 = A2[0] + A2[1] + A2[2] + A2[3];
        xrow[p][oe]      = x[n * 24 + oe]      + a0 + sB[oe];
        xrow[p][oe + 8]  = x[n * 24 + oe + 8]  + a1 + sB[oe + 8];
        xrow[p][oe + 16] = x[n * 24 + oe + 16] + a2 + sB[oe + 16];
    }
    float mu, rstd;
    {
        float s = xrow[p][oe] + xrow[p][oe + 8] + xrow[p][oe + 16];
        s += __shfl_xor(s, 1); s += __shfl_xor(s, 2); s += __shfl_xor(s, 4);
        mu = s / 24.0f;
        float v0 = xrow[p][oe] - mu, v1 = xrow[p][oe + 8] - mu, v2 = xrow[p][oe + 16] - mu;
        float v = v0 * v0 + v1 * v1 + v2 * v2;
        v += __shfl_xor(v, 1); v += __shfl_xor(v, 2); v += __shfl_xor(v, 4);
        rstd = 1.0f / sqrtf(v / 24.0f + 1e-5f);
    }
    h2row[p][oe]      = (xrow[p][oe] - mu)      * rstd * sB[24 + oe]      + sB[48 + oe];
    h2row[p][oe + 8]  = (xrow[p][oe + 8] - mu)  * rstd * sB[24 + oe + 8]  + sB[48 + oe + 8];
    h2row[p][oe + 16] = (xrow[p][oe + 16] - mu) * rstd * sB[24 + oe + 16] + sB[48 + oe + 16];
    {
        const floatx4* hp = (const floatx4*)&h2row[p][0];
        const floatx4* w0p = (const floatx4*)&sW1T[oe][0];
        const floatx4* w1p = (const floatx4*)&sW1T[oe + 8][0];
        const floatx4* w2p = (const floatx4*)&sW1T[oe + 16][0];
        floatx4 A0 = {0.f, 0.f, 0.f, 0.f}, A1 = A0, A2 = A0;
#pragma unroll
        for (int ii = 0; ii < 6; ii++) {
            floatx4 hv = hp[ii];
            A0 += hv * w0p[ii];
            A1 += hv * w1p[ii];
            A2 += hv * w2p[ii];
        }
        ffrow[p][oe]      = fmaxf(A0[0]+A0[1]+A0[2]+A0[3] + sB[72 + oe], 0.f);
        ffrow[p][oe + 8]  = fmaxf(A1[0]+A1[1]+A1[2]+A1[3] + sB[72 + oe + 8], 0.f);
        ffrow[p][oe + 16] = fmaxf(A2[0]+A2[1]+A2[2]+A2[3] + sB[72 + oe + 16], 0.f);
    }
    {
        const floatx4* fp = (const floatx4*)&ffrow[p][0];
        const floatx4* w0p = (const floatx4*)&sW2T[oe][0];
        const floatx4* w1p = (const floatx4*)&sW2T[oe + 8][0];
        const floatx4* w2p = (const floatx4*)&sW2T[oe + 16][0];
        floatx4 A0 = {0.f, 0.f, 0.f, 0.f}, A1 = A0, A2 = A0;
#pragma unroll
        for (int ii = 0; ii < 6; ii++) {
            floatx4 fv = fp[ii];
            A0 += fv * w0p[ii];
            A1 += fv * w1p[ii];
            A2 += fv * w2p[ii];
        }
        out[n * 24 + oe]      = xrow[p][oe]      + A0[0]+A0[1]+A0[2]+A0[3] + sB[96 + oe];
        out[n * 24 + oe + 8]  = xrow[p][oe + 8]  + A1[0]+A1[1]+A1[2]+A1[3] + sB[96 + oe + 8];
        out[n * 24 + oe + 16] = xrow[p][oe + 16] + A2[0]+A2[1]+A2[2]+A2[3] + sB[96 + oe + 16];
    }
}

extern "C" void kernel_launch(void* const* d_in, const int* in_sizes, int n_in,
                              void* d_out, int out_size, void* d_ws, size_t ws_size,
                              hipStream_t stream) {
    const float* x      = (const float*)d_in[0];
    const float* coords = (const float*)d_in[1];
    const float* n1g    = (const float*)d_in[2];
    const float* n1b    = (const float*)d_in[3];
    const float* Wq     = (const float*)d_in[4];
    const float* Wk     = (const float*)d_in[5];
    const float* Wv     = (const float*)d_in[6];
    const float* wrpe   = (const float*)d_in[7];
    const float* Wo     = (const float*)d_in[8];
    const float* bo     = (const float*)d_in[9];
    const float* n2g    = (const float*)d_in[10];
    const float* n2b    = (const float*)d_in[11];
    const float* W1     = (const float*)d_in[12];
    const float* b1     = (const float*)d_in[13];
    const float* W2     = (const float*)d_in[14];
    const float* b2     = (const float*)d_in[15];
    const float* alphas = (const float*)d_in[16];

    char* ws = (char*)d_ws;
    size_t off = 0;
    auto alloc = [&](size_t bytes) -> void* {
        void* p = ws + off;
        off = (off + bytes + 255) & ~(size_t)255;
        return p;
    };
    double* w64   = (double*)alloc(256);
    double* cqp   = (double*)alloc(256);
    double* Aq    = (double*)alloc(24 * NRH * 8);
    double* Ak    = (double*)alloc(24 * NRH * 8);
    double* ct    = (double*)alloc(NRH * 4 * 8);
    float*  xnf   = (float*)alloc((size_t)NPT * 24 * 4);
    ushort* qhatB = (ushort*)alloc((size_t)NH * NPT * 32 * 2);
    ushort* khatB = (ushort*)alloc((size_t)NH * NPT * 32 * 2);
    ushort* varrB = (ushort*)alloc((size_t)NH * NPT * 32 * 2);
    u64*    keys  = (u64*)alloc((size_t)NSEG * NPT * 8);
    u64*    keys2 = (u64*)alloc((size_t)NSEG * NPT * 8);
    ushort* ozB   = (ushort*)alloc((size_t)NHASH * NH * NPT * 32 * 2);
    if (off > ws_size) return;

    k0b<<<1, 256, 0, stream>>>(wrpe, Wq, Wk, alphas, w64, cqp, Aq, Ak, ct);
    k2s<<<NPT / 64, 512, 0, stream>>>(x, n1g, n1b, coords, Aq, Ak, ct, w64, keys, xnf);
    k2p_sort<<<192 + NPT / K2P_PTS, 1024, 0, stream>>>(keys, xnf, Wq, Wk, Wv, coords,
                                                       w64, cqp, qhatB, khatB, varrB);
    sort_tail1_fused<<<192, 1024, 0, stream>>>(keys);
    sort_corank<<<NSEG * 256, 128, 0, stream>>>(keys, keys2);
    k3_attn<<<256 * 8 * 3, 256, 0, stream>>>(keys2, qhatB, khatB, varrB, ozB);
    k4_final<<<NPT / K4PTS, 256, 0, stream>>>(ozB, x, Wo, bo, n2g, n2b,
                                              W1, b1, W2, b2, (float*)d_out);
}

// Round 10
// 284.217 us; speedup vs baseline: 1.0283x; 1.0283x over previous
//
#include <hip/hip_runtime.h>
#include <math.h>

#define NPT 32768
#define NH 8
#define HD 24
#define EDIM 28
#define NHASH 3
#define NSEG 48
#define NRH 24   // N_HASHES * NUM_HEADS = 24 alpha rows

typedef unsigned long long u64;
typedef unsigned short ushort;
typedef __attribute__((__vector_size__(8 * sizeof(short)))) short bf16x8;
typedef __attribute__((__vector_size__(4 * sizeof(float)))) float floatx4;
typedef __attribute__((__vector_size__(4 * sizeof(unsigned int)))) unsigned int uint32x4;

__device__ __forceinline__ ushort f2bf(float f) {
    unsigned u = __float_as_uint(f);
    unsigned r = u + 0x7FFF + ((u >> 16) & 1);
    return (ushort)(r >> 16);
}
__device__ __forceinline__ float us2f(ushort u) {
    return __uint_as_float(((unsigned)u) << 16);
}

// ---------------- K0b: RPE weights + folded score matrices (fp64) ----------------
__global__ __launch_bounds__(256) void k0b(
    const float* __restrict__ wrpe, const float* __restrict__ Wq,
    const float* __restrict__ Wk, const float* __restrict__ alphas,
    double* __restrict__ w64, double* __restrict__ cqp64,
    double* __restrict__ Aq, double* __restrict__ Ak, double* __restrict__ ct) {
    __shared__ double sw[16], sc[16];
    int t = threadIdx.x;
    if (t < 16) {
        int h = t >> 1, c = t & 1;
        double s = 0.0;
        for (int i = 0; i < 24; i++)
            for (int j = 0; j < 8; j++)
                s += (double)wrpe[(h * 24 + i) * 16 + c * 8 + j];
        double m = s / 192.0;
        sw[t] = m * m;
        sc[t] = sqrt(2.0) * fabs(m);
        w64[t] = sw[t];
        cqp64[t] = sc[t];
    }
    __syncthreads();
    const double QSCALE = 1.0 / sqrt(24.0);
    for (int idx = t; idx < 24 * NRH; idx += 256) {
        int i = idx / NRH, rh = idx % NRH;
        int h = rh & 7;
        double aq = 0.0, ak = 0.0;
        for (int e = 0; e < 24; e++) {
            double al = (double)alphas[rh * 28 + e];
            aq += (double)Wq[i * 192 + h * 24 + e] * al;
            ak += (double)Wk[i * 192 + h * 24 + e] * al;
        }
        Aq[idx] = aq * QSCALE;
        Ak[idx] = ak;
    }
    if (t < NRH) {
        int h = t & 7;
        ct[t * 4 + 0] = (double)alphas[t * 28 + 24] * sc[h * 2 + 0];
        ct[t * 4 + 1] = (double)alphas[t * 28 + 25] * sc[h * 2 + 1];
        ct[t * 4 + 2] = (double)alphas[t * 28 + 26];
        ct[t * 4 + 3] = (double)alphas[t * 28 + 27];
    }
}

// ---------------- K2s: fused fp64 LN + hash scores + xnf emit ----------------
__global__ __launch_bounds__(512) void k2s(
    const float* __restrict__ x, const float* __restrict__ n1g,
    const float* __restrict__ n1b, const float* __restrict__ coords,
    const double* __restrict__ Aq, const double* __restrict__ Ak,
    const double* __restrict__ ct, const double* __restrict__ w64,
    u64* __restrict__ keys, float* __restrict__ xnf) {
    __shared__ double sA[2][24][NRH];
    __shared__ double sCt[NRH][4];
    __shared__ double sW64[16];
    __shared__ double sGB[48];
    __shared__ double sXn[8][24];
    int t = threadIdx.x;
    for (int i = t; i < 24 * NRH; i += 512) sA[0][i / NRH][i % NRH] = Aq[i];
    for (int i = t; i < 24 * NRH; i += 512) sA[1][i / NRH][i % NRH] = Ak[i];
    for (int i = t; i < NRH * 4; i += 512) sCt[i / 4][i % 4] = ct[i];
    if (t < 16) sW64[t] = w64[t];
    if (t < 24) { sGB[t] = (double)n1g[t]; sGB[24 + t] = (double)n1b[t]; }
    __syncthreads();
    int wv = t >> 6, l = t & 63;
    for (int g = 0; g < 8; g++) {
        int n = blockIdx.x * 64 + g * 8 + wv;
        double xv = (l < 24) ? (double)x[(u64)n * 24 + l] : 0.0;
        double s = xv;
        s += __shfl_xor(s, 1); s += __shfl_xor(s, 2); s += __shfl_xor(s, 4);
        s += __shfl_xor(s, 8); s += __shfl_xor(s, 16);
        double mu = s / 24.0;
        double d = (l < 24) ? (xv - mu) : 0.0;
        double v2 = d * d;
        v2 += __shfl_xor(v2, 1); v2 += __shfl_xor(v2, 2); v2 += __shfl_xor(v2, 4);
        v2 += __shfl_xor(v2, 8); v2 += __shfl_xor(v2, 16);
        double rstd = 1.0 / sqrt(v2 / 24.0 + 1e-5);
        if (l < 24) {
            double xn = d * rstd * sGB[l] + sGB[24 + l];
            sXn[wv][l] = xn;
            xnf[(u64)n * 24 + l] = (float)xn;
        }
        // no barrier: sXn[wv] written and read by the same wave only
        double p0 = (double)coords[(u64)n * 3 + 1];
        double p1 = (double)coords[(u64)n * 3 + 2];
        if (l < 2 * NRH) {
            int qk = l / NRH, rh = l % NRH;
            int h = rh & 7;
            double sqn = sW64[2 * h] * p0 * p0 + sW64[2 * h + 1] * p1 * p1;
            double acc = sCt[rh][0] * p0 + sCt[rh][1] * p1;
            acc += qk ? (sCt[rh][2] - sqn * sCt[rh][3]) : (sCt[rh][3] - sqn * sCt[rh][2]);
            for (int i = 0; i < 24; i++) acc += sXn[wv][i] * sA[qk][i][rh];
            u64 u = (u64)__double_as_longlong(acc);
            if (u >> 63) u = ~u; else u |= 0x8000000000000000ULL;
            u64 key = (u & ~(u64)32767) | (u64)n;
            keys[(u64)l * NPT + n] = key;  // segment = qk*24 + rh = l
        }
    }
}

// ---------------- Bitonic sort helpers ----------------
__device__ __forceinline__ u64 shflx64(u64 v, int d) {
    int lo = __shfl_xor((int)(unsigned)v, d);
    int hi = __shfl_xor((int)(unsigned)(v >> 32), d);
    return ((u64)(unsigned)hi << 32) | (unsigned)lo;
}
__device__ __forceinline__ void cswap(u64& a, u64& b, bool up) {
    if ((a > b) == up) { u64 tmp = a; a = b; b = tmp; }
}
__device__ __forceinline__ u64* sslot(u64* s, int i) {
    int a = i << 3;
    a ^= ((a >> 9) & 7) << 4;
    return (u64*)((char*)s + a);
}
__device__ __forceinline__ void reg_passes(u64 e[8], int ib, int K, int jmax) {
    for (int j = jmax; j >= 1; j >>= 1) {
#pragma unroll
        for (int k = 0; k < 8; k++)
            if ((k & j) == 0) cswap(e[k], e[k | j], ((ib + k) & K) == 0);
    }
}
__device__ __forceinline__ void shfl_passes(u64 e[8], int t, int segoff, int K, int jhi, int jlo) {
    for (int j = jhi; j >= jlo; j >>= 1) {
        int d = j >> 3;
        bool lower = (t & d) == 0;
        bool up = ((segoff + ((t & ~d) << 3)) & K) == 0;
        bool keepmin = (lower == up);
#pragma unroll
        for (int k = 0; k < 8; k++) {
            u64 o = shflx64(e[k], d);
            bool ownsm = e[k] < o;
            e[k] = (ownsm == keepmin) ? e[k] : o;
        }
    }
}

// ---------------- Fused K2p + sort_local_full ----------------
// blockIdx < 192: full bitonic sort of one 8192-key chunk (unchanged logic).
// blockIdx >= 192: k2p projections for 32 points.
// __launch_bounds__(1024, 4): 16-wave block = 4 waves/EU = 1 block/CU ->
// VGPR cap 128/wave, guaranteeing the k2p path's wc[24] column stays in
// registers (no scratch spill under a 2-block/CU 64-VGPR budget).
#define K2P_PTS 32
#define INVLN2F 1.4426950408889634f
__global__ __launch_bounds__(1024, 4) void k2p_sort(
    u64* keys,
    const float* __restrict__ xnf,
    const float* __restrict__ Wq, const float* __restrict__ Wk,
    const float* __restrict__ Wv, const float* __restrict__ coords,
    const double* __restrict__ w64, const double* __restrict__ cqp64,
    ushort* __restrict__ qhatB, ushort* __restrict__ khatB, ushort* __restrict__ varrB) {
    __shared__ __align__(16) char smem[65536];
    int t = threadIdx.x;
    if (blockIdx.x < 192) {
        // ---------- sort_local_full path ----------
        u64* s = (u64*)smem;
        u64 gbase = (u64)blockIdx.x * 8192;
        int segoff = (int)(gbase & 32767);
        int ib = segoff + t * 8;
        u64 e[8];
#pragma unroll
        for (int k = 0; k < 8; k++) e[k] = keys[gbase + t * 8 + k];
        reg_passes(e, ib, 2, 1);
        reg_passes(e, ib, 4, 2);
        reg_passes(e, ib, 8, 4);
        for (int K = 16; K <= 512; K <<= 1) {
            shfl_passes(e, t, segoff, K, K >> 1, 8);
            reg_passes(e, ib, K, 4);
        }
#pragma unroll
        for (int k = 0; k < 8; k++) *sslot(s, t * 8 + k) = e[k];
        __syncthreads();
        for (int K = 1024; K <= 8192; K <<= 1) {
            for (int j = K >> 1; j >= 512; j >>= 1) {
                for (int p = t; p < 4096; p += 1024) {
                    int i = ((p & ~(j - 1)) << 1) | (p & (j - 1));
                    int i2 = i | j;
                    bool up = (((segoff + i) & K) == 0);
                    u64 a = *sslot(s, i), b = *sslot(s, i2);
                    if ((a > b) == up) { *sslot(s, i) = b; *sslot(s, i2) = a; }
                }
                __syncthreads();
            }
#pragma unroll
            for (int k = 0; k < 8; k++) e[k] = *sslot(s, t * 8 + k);
            shfl_passes(e, t, segoff, K, 256, 8);
            reg_passes(e, ib, K, 4);
            if (K < 8192) {
#pragma unroll
                for (int k = 0; k < 8; k++) *sslot(s, t * 8 + k) = e[k];
                __syncthreads();
            } else {
#pragma unroll
                for (int k = 0; k < 8; k++) keys[gbase + t * 8 + k] = e[k];
            }
        }
    } else {
        // ---------- k2p path ----------
        ushort* sT = (ushort*)smem;   // [arr][h][pt][e] 49152 B
        int n0 = (blockIdx.x - 192) * K2P_PTS;
        if (t < 576) {
            int m = t / 192, jj = t % 192;
            const float* W = (m == 0) ? Wq : ((m == 1) ? Wk : Wv);
            float wc[24];
#pragma unroll
            for (int i = 0; i < 24; i++) wc[i] = W[i * 192 + jj];
            const float scale = (m == 0) ? (float)(1.4426950408889634 / sqrt(24.0)) : 1.0f;
            int h = jj / 24, e = jj % 24;
            ushort* sbase = sT + ((m * 8 + h) * K2P_PTS) * 32 + e;
            for (int p = 0; p < K2P_PTS; p++) {
                int n = n0 + p;
                const float* xr = xnf + (u64)n * 24;   // wave-uniform -> s_load
                float acc = 0.f;
#pragma unroll
                for (int i = 0; i < 24; i++) acc += xr[i] * wc[i];
                sbase[p * 32] = f2bf(acc * scale);
            }
        } else if (t < 640) {
            int l = t - 576;
            int h2 = l >> 3, e2 = 24 + (l & 7);
            double c0 = cqp64[h2 * 2], c1 = cqp64[h2 * 2 + 1];
            double wa = w64[h2 * 2], wb = w64[h2 * 2 + 1];
            ushort* qb = sT + ((0 * 8 + h2) * K2P_PTS) * 32 + e2;
            ushort* kb = sT + ((1 * 8 + h2) * K2P_PTS) * 32 + e2;
            ushort* vb = sT + ((2 * 8 + h2) * K2P_PTS) * 32 + e2;
            for (int p = 0; p < K2P_PTS; p++) {
                int n = n0 + p;
                double p0 = (double)coords[(u64)n * 3 + 1];
                double p1 = (double)coords[(u64)n * 3 + 2];
                float qv, kv;
                if (e2 < 26) {
                    int c = e2 - 24;
                    float qp = (float)((c ? c1 : c0) * (c ? p1 : p0));
                    qv = qp; kv = qp;
                } else if (e2 < 28) {
                    double sqn = wa * p0 * p0 + wb * p1 * p1;
                    if (e2 == 26) { qv = (float)(-sqn); kv = 1.0f; }
                    else          { qv = 1.0f; kv = (float)(-sqn); }
                } else {
                    qv = 0.0f; kv = 0.0f;
                }
                qb[p * 32] = f2bf(qv * INVLN2F);   // q-side 1/ln2 prescale
                kb[p * 32] = f2bf(kv);
                vb[p * 32] = 0;   // init pad cols of varr slab (copied out; not read)
            }
        }
        __syncthreads();
        // coalesced copy-out: 24 slabs x 128 16B-chunks = 3072.
        for (int c = t; c < 3 * 8 * K2P_PTS * 4; c += 1024) {
            int arrh = c >> 7, off = c & 127;
            int arr = arrh >> 3, hh = arrh & 7;
            uint32x4 v = *(const uint32x4*)(sT + arrh * (K2P_PTS * 32) + off * 8);
            ushort* op = (arr == 0) ? qhatB : ((arr == 1) ? khatB : varrB);
            *(uint32x4*)(op + (u64)hh * NPT * 32 + (u64)n0 * 32 + off * 8) = v;
        }
    }
}

// tail1 fused with the K=16384 j=8192 global pass: load own chunk + partner,
// keep min/max per element (keepmin for chunk-in-segment 0,3; max for 1,2),
// then run the K=16384 merge j=4096..1 (full sort of the 8192-chunk's role).
// After this kernel: segment first 16384 fully ASCENDING, second 16384 DESCENDING.
__global__ __launch_bounds__(1024) void sort_tail1_fused(u64* keys) {
    __shared__ u64 s[8192];
    int t = threadIdx.x;
    u64 gbase = (u64)blockIdx.x * 8192;
    u64 pbase = gbase ^ 8192ULL;          // partner chunk at distance j=8192
    int ci = (int)((gbase >> 13) & 3);    // chunk index within 32768-segment
    bool keepmin = (ci == 0) || (ci == 3);
    int segoff = (int)(gbase & 32767);
    int ib = segoff + t * 8;
    for (int i = t; i < 8192; i += 1024) {
        u64 a = keys[gbase + i];
        u64 b = keys[pbase + i];
        u64 mn = a < b ? a : b;
        u64 mx = a < b ? b : a;
        *sslot(s, i) = keepmin ? mn : mx;
    }
    __syncthreads();
    const int K = 16384;
    for (int j = 4096; j >= 512; j >>= 1) {
        for (int p = t; p < 4096; p += 1024) {
            int i = ((p & ~(j - 1)) << 1) | (p & (j - 1));
            int i2 = i | j;
            bool up = (((segoff + i) & K) == 0);
            u64 a = *sslot(s, i), b = *sslot(s, i2);
            if ((a > b) == up) { *sslot(s, i) = b; *sslot(s, i2) = a; }
        }
        __syncthreads();
    }
    u64 e[8];
#pragma unroll
    for (int k = 0; k < 8; k++) e[k] = *sslot(s, t * 8 + k);
    shfl_passes(e, t, segoff, K, 256, 8);
    reg_passes(e, ib, K, 4);
#pragma unroll
    for (int k = 0; k < 8; k++) keys[gbase + t * 8 + k] = e[k];
}

// ---------------- co-rank partition (verified round 9, now inlined into k3) ----------------
// Segment after tail1 = run A (16384 asc) ++ run B (16384 desc).
// corank(r): unique a with A[a-1] < B'[r-a] and B'[r-a-1] < A[a]
// (B'[i] = B[16383-i] ascending; keys distinct since low 15 bits = index).
__device__ __forceinline__ int corank(int r, const u64* __restrict__ A,
                                      const u64* __restrict__ B) {
    int lo = r - 16384; if (lo < 0) lo = 0;
    int hi = r < 16384 ? r : 16384;
    while (lo < hi) {
        int a = (lo + hi + 1) >> 1;          // a >= 1 in-loop
        int b = r - a;                        // 0 <= b < 16384 in-loop
        u64 Bv = B[16383 - b];                // B'[b]
        if (A[a - 1] < Bv) lo = a; else hi = a - 1;
    }
    return lo;
}

// ---------------- K3: block attention via bf16 MFMA ----------------
// v9: co-rank partition computed in-block (threads 0/64/128/192, one search
// each, 4 different waves) -> sort_corank kernel + keys2 round-trip deleted.
// Rest = round-5 passing v2 structure + exp2f softmax.
__global__ __launch_bounds__(256, 4) void k3_attn(
    const u64* __restrict__ keys, const ushort* __restrict__ qhatB,
    const ushort* __restrict__ khatB, const ushort* __restrict__ varrB,
    ushort* __restrict__ ozB) {
    int rh3 = blockIdx.x % 24;
    int b = blockIdx.x / 24;
    int h = rh3 & 7, r = rh3 >> 3;
    __shared__ __align__(16) char smem[6144 + 32768 + 512 + 16];
    char* sVt = smem;                       // 24 rows x 256 B (phi-permuted, swizzled)
    char* sP  = smem + 6144;                // 128 rows x 256 B (phi-permuted, swizzled)
    ushort* qidx = (ushort*)(smem + 6144 + 32768);
    ushort* kidx = qidx + 128;
    int* sh = (int*)(smem + 6144 + 32768 + 512);
    int t = threadIdx.x;
    int segQ = r * 8 + h, segK = 24 + r * 8 + h;
    int r0 = b * 128;
    const u64* AQ = keys + (u64)segQ * NPT;
    const u64* BQ = AQ + 16384;
    const u64* AK = keys + (u64)segK * NPT;
    const u64* BK = AK + 16384;
    if (t == 0)        sh[0] = corank(r0, AQ, BQ);
    else if (t == 64)  sh[1] = corank(r0 + 128, AQ, BQ);
    else if (t == 128) sh[2] = corank(r0, AK, BK);
    else if (t == 192) sh[3] = corank(r0 + 128, AK, BK);
    __syncthreads();
    if (t < 128) {
        int aLo = sh[0], na = sh[1] - aLo, bLo = r0 - aLo;
        u64 v = (t < na) ? AQ[aLo + t] : BQ[16383 - (bLo + (t - na))];
        qidx[t] = (ushort)(v & 32767ULL);
    } else {
        int i = t - 128;
        int aLo = sh[2], na = sh[3] - aLo, bLo = r0 - aLo;
        u64 v = (i < na) ? AK[aLo + i] : BK[16383 - (bLo + (i - na))];
        kidx[i] = (ushort)(v & 32767ULL);
    }
    __syncthreads();

    int wave = t >> 6, L = t & 63;
    int quad = L >> 4, n16 = L & 15;

    const bf16x8* Qg = (const bf16x8*)(qhatB + (u64)h * NPT * 32);
    const bf16x8* Kg = (const bf16x8*)(khatB + (u64)h * NPT * 32);
    bf16x8 afr[2];
#pragma unroll
    for (int rtg = 0; rtg < 2; rtg++) {
        int qi = qidx[wave * 32 + rtg * 16 + n16];
        afr[rtg] = Qg[(u64)qi * 4 + quad];
    }
    bf16x8 bfr[8];
#pragma unroll
    for (int ct = 0; ct < 8; ct++) {
        int ki = kidx[ct * 16 + n16];
        bfr[ct] = Kg[(u64)ki * 4 + quad];
    }
    // stage V^T into phi-permuted + swizzled layout: key t -> byte col
    // phi(t)*2 = ((t&15)<<4)|((t>>4)<<1); per-row XOR (e&7)<<4.
    if (t < 128) {
        int ki = kidx[t];
        const bf16x8* vr = (const bf16x8*)(varrB + ((u64)h * NPT + ki) * 32);
        bf16x8 v0 = vr[0], v1 = vr[1], v2 = vr[2];
        int colb = ((t & 15) << 4) | ((t >> 4) << 1);
#pragma unroll
        for (int e = 0; e < 8; e++) {
            int e0 = e, e1 = 8 + e, e2 = 16 + e;
            *(short*)(sVt + e0 * 256 + (colb ^ ((e0 & 7) << 4))) = v0[e];
            *(short*)(sVt + e1 * 256 + (colb ^ ((e1 & 7) << 4))) = v1[e];
            *(short*)(sVt + e2 * 256 + (colb ^ ((e2 & 7) << 4))) = v2[e];
        }
    }
    __syncthreads();

    floatx4 acc[2][8];
#pragma unroll
    for (int rtg = 0; rtg < 2; rtg++)
#pragma unroll
        for (int ct = 0; ct < 8; ct++)
            acc[rtg][ct] = (floatx4){0.f, 0.f, 0.f, 0.f};
#pragma unroll
    for (int ct = 0; ct < 8; ct++) {
#pragma unroll
        for (int rtg = 0; rtg < 2; rtg++)
            acc[rtg][ct] = __builtin_amdgcn_mfma_f32_16x16x32_bf16(afr[rtg], bfr[ct], acc[rtg][ct], 0, 0, 0);
    }

    // Softmax (scores in log2 units; exp2f = native v_exp_f32).
    float mrow[2][4], srow[2][4];
#pragma unroll
    for (int rtg = 0; rtg < 2; rtg++) {
#pragma unroll
        for (int rg = 0; rg < 4; rg++) {
            float m = acc[rtg][0][rg];
#pragma unroll
            for (int ct = 1; ct < 8; ct++) m = fmaxf(m, acc[rtg][ct][rg]);
            m = fmaxf(m, __shfl_xor(m, 1));
            m = fmaxf(m, __shfl_xor(m, 2));
            m = fmaxf(m, __shfl_xor(m, 4));
            m = fmaxf(m, __shfl_xor(m, 8));
            mrow[rtg][rg] = m;
            float p[8];
            float s = 0.0f;
#pragma unroll
            for (int ct = 0; ct < 8; ct++) {
                p[ct] = exp2f(acc[rtg][ct][rg] - m);
                s += p[ct];
            }
            s += __shfl_xor(s, 1);
            s += __shfl_xor(s, 2);
            s += __shfl_xor(s, 4);
            s += __shfl_xor(s, 8);
            srow[rtg][rg] = s;
            unsigned w0, w1, w2, w3;
            asm("v_cvt_pk_bf16_f32 %0, %1, %2" : "=v"(w0) : "v"(p[0]), "v"(p[1]));
            asm("v_cvt_pk_bf16_f32 %0, %1, %2" : "=v"(w1) : "v"(p[2]), "v"(p[3]));
            asm("v_cvt_pk_bf16_f32 %0, %1, %2" : "=v"(w2) : "v"(p[4]), "v"(p[5]));
            asm("v_cvt_pk_bf16_f32 %0, %1, %2" : "=v"(w3) : "v"(p[6]), "v"(p[7]));
            int row = wave * 32 + rtg * 16 + quad * 4 + rg;
            uint32x4 pk = {w0, w1, w2, w3};
            *(uint32x4*)(sP + row * 256 + (((n16 << 4)) ^ ((row & 7) << 4))) = pk;
        }
    }
    // sP written and read by the same wave only -> no barrier needed.

    floatx4 occ[2][2];
#pragma unroll
    for (int rtg = 0; rtg < 2; rtg++)
#pragma unroll
        for (int ct2 = 0; ct2 < 2; ct2++)
            occ[rtg][ct2] = (floatx4){0.f, 0.f, 0.f, 0.f};
#pragma unroll
    for (int ks = 0; ks < 4; ks++) {
        int kb = ks * 64 + quad * 16;   // byte offset of this lane's 8 phys cols
        bf16x8 bv[2], av[2];
#pragma unroll
        for (int ct2 = 0; ct2 < 2; ct2++) {
            int e = ct2 * 16 + n16;
            int ec = (e < 24) ? e : 0;  // cols 24..31 discarded; clamp keeps reads in sVt
            bv[ct2] = *(const bf16x8*)(sVt + ec * 256 + (kb ^ ((ec & 7) << 4)));
        }
#pragma unroll
        for (int rtg = 0; rtg < 2; rtg++) {
            int rowA = wave * 32 + rtg * 16 + n16;
            av[rtg] = *(const bf16x8*)(sP + rowA * 256 + (kb ^ ((rowA & 7) << 4)));
        }
#pragma unroll
        for (int rtg = 0; rtg < 2; rtg++)
#pragma unroll
            for (int ct2 = 0; ct2 < 2; ct2++)
                occ[rtg][ct2] = __builtin_amdgcn_mfma_f32_16x16x32_bf16(av[rtg], bv[ct2], occ[rtg][ct2], 0, 0, 0);
    }

    const float LN2F = 0.6931471805599453f;
#pragma unroll
    for (int rtg = 0; rtg < 2; rtg++) {
#pragma unroll
        for (int rg = 0; rg < 4; rg++) {
            int row = wave * 32 + rtg * 16 + quad * 4 + rg;
            int oi = qidx[row];
            float inv = 1.0f / srow[rtg][rg];
            ushort* orow = ozB + ((u64)segQ * NPT + oi) * 32;
#pragma unroll
            for (int ct2 = 0; ct2 < 2; ct2++) {
                int col = ct2 * 16 + n16;
                if (col < 24) orow[col] = f2bf(occ[rtg][ct2][rg] * inv);
            }
            if (n16 == 0)
                *(float*)(orow + 24) = mrow[rtg][rg] * LN2F + __logf(srow[rtg][rg]);
        }
    }
}

// ---------------- K4: hash combine + Wo + residual + LN2 + FFN (fp32, 32 pts/block) ----------------
#define K4PTS 32
#define AT_STR 196   // floats; 16B-aligned rows
#define W_STR 28     // transposed small-matrix row stride (16B-aligned)
__global__ __launch_bounds__(256) void k4_final(
    const ushort* __restrict__ ozB,
    const float* __restrict__ x,
    const float* __restrict__ Wo, const float* __restrict__ bo,
    const float* __restrict__ g2, const float* __restrict__ b2,
    const float* __restrict__ W1, const float* __restrict__ b1f,
    const float* __restrict__ W2, const float* __restrict__ b2f,
    float* __restrict__ out) {
    __shared__ __align__(16) float sWoT[24][AT_STR];
    __shared__ __align__(16) float sW1T[24][W_STR], sW2T[24][W_STR];
    __shared__ float sB[5 * 24];
    __shared__ __align__(16) float attn[K4PTS][AT_STR];
    __shared__ float xrow[K4PTS][25];
    __shared__ __align__(16) float h2row[K4PTS][W_STR];
    __shared__ __align__(16) float ffrow[K4PTS][W_STR];
    int t = threadIdx.x;
    int base = blockIdx.x * K4PTS;
    for (int i = t; i < 4608; i += 256) sWoT[i % 24][i / 24] = Wo[i];
    for (int i = t; i < 576; i += 256) {
        sW1T[i % 24][i / 24] = W1[i];   // sW1T[out][in]
        sW2T[i % 24][i / 24] = W2[i];
    }
    if (t < 24) {
        sB[t] = bo[t]; sB[24 + t] = g2[t]; sB[48 + t] = b2[t];
        sB[72 + t] = b1f[t]; sB[96 + t] = b2f[t];
    }
    // zero the pad columns so float4 reads over 24..27 are benign
    if (t < K4PTS * 4) {
        int p = t >> 2, c = 24 + (t & 3);
        h2row[p][c] = 0.f; ffrow[p][c] = 0.f;
    }
    if (t < 24 * 4) {
        int rr = t >> 2, c = 24 + (t & 3);
        sW1T[rr][c] = 0.f; sW2T[rr][c] = 0.f;
    }
    {
        int p = t >> 3, h = t & 7;
        int n = base + p;
        const ushort* r0 = ozB + ((u64)(0 * 8 + h) * NPT + n) * 32;
        const ushort* r1 = ozB + ((u64)(1 * 8 + h) * NPT + n) * 32;
        const ushort* r2 = ozB + ((u64)(2 * 8 + h) * NPT + n) * 32;
        float z0 = *(const float*)(r0 + 24);
        float z1 = *(const float*)(r1 + 24);
        float z2 = *(const float*)(r2 + 24);
        float zm = fmaxf(z0, fmaxf(z1, z2));
        float e0 = __expf(z0 - zm), e1 = __expf(z1 - zm), e2 = __expf(z2 - zm);
        float inv = 1.0f / (e0 + e1 + e2);
        float w0 = e0 * inv, w1 = e1 * inv, w2 = e2 * inv;
#pragma unroll
        for (int e = 0; e < 24; e++)
            attn[p][h * 24 + e] = w0 * us2f(r0[e]) + w1 * us2f(r1[e]) + w2 * us2f(r2[e]);
    }
    __syncthreads();
    int p = t >> 3, oe = t & 7;
    int n = base + p;
    {
        const floatx4* ap = (const floatx4*)&attn[p][0];
        const floatx4* w0p = (const floatx4*)&sWoT[oe][0];
        const floatx4* w1p = (const floatx4*)&sWoT[oe + 8][0];
        const floatx4* w2p = (const floatx4*)&sWoT[oe + 16][0];
        floatx4 A0 = {0.f, 0.f, 0.f, 0.f}, A1 = A0, A2 = A0;
        for (int ii = 0; ii < 48; ii++) {
            floatx4 av = ap[ii];
            A0 += av * w0p[ii];
            A1 += av * w1p[ii];
            A2 += av * w2p[ii];
        }
        float a0 = A0[0] + A0[1] + A0[2] + A0[3];
        float a1 = A1[0] + A1[1] + A1[2] + A1[3];
        float a2 = A2[0] + A2[1] + A2[2] + A2[3];
        xrow[p][oe]      = x[n * 24 + oe]      + a0 + sB[oe];
        xrow[p][oe + 8]  = x[n * 24 + oe + 8]  + a1 + sB[oe + 8];
        xrow[p][oe + 16] = x[n * 24 + oe + 16] + a2 + sB[oe + 16];
    }
    float mu, rstd;
    {
        float s = xrow[p][oe] + xrow[p][oe + 8] + xrow[p][oe + 16];
        s += __shfl_xor(s, 1); s += __shfl_xor(s, 2); s += __shfl_xor(s, 4);
        mu = s / 24.0f;
        float v0 = xrow[p][oe] - mu, v1 = xrow[p][oe + 8] - mu, v2 = xrow[p][oe + 16] - mu;
        float v = v0 * v0 + v1 * v1 + v2 * v2;
        v += __shfl_xor(v, 1); v += __shfl_xor(v, 2); v += __shfl_xor(v, 4);
        rstd = 1.0f / sqrtf(v / 24.0f + 1e-5f);
    }
    h2row[p][oe]      = (xrow[p][oe] - mu)      * rstd * sB[24 + oe]      + sB[48 + oe];
    h2row[p][oe + 8]  = (xrow[p][oe + 8] - mu)  * rstd * sB[24 + oe + 8]  + sB[48 + oe + 8];
    h2row[p][oe + 16] = (xrow[p][oe + 16] - mu) * rstd * sB[24 + oe + 16] + sB[48 + oe + 16];
    {
        const floatx4* hp = (const floatx4*)&h2row[p][0];
        const floatx4* w0p = (const floatx4*)&sW1T[oe][0];
        const floatx4* w1p = (const floatx4*)&sW1T[oe + 8][0];
        const floatx4* w2p = (const floatx4*)&sW1T[oe + 16][0];
        floatx4 A0 = {0.f, 0.f, 0.f, 0.f}, A1 = A0, A2 = A0;
#pragma unroll
        for (int ii = 0; ii < 6; ii++) {
            floatx4 hv = hp[ii];
            A0 += hv * w0p[ii];
            A1 += hv * w1p[ii];
            A2 += hv * w2p[ii];
        }
        ffrow[p][oe]      = fmaxf(A0[0]+A0[1]+A0[2]+A0[3] + sB[72 + oe], 0.f);
        ffrow[p][oe + 8]  = fmaxf(A1[0]+A1[1]+A1[2]+A1[3] + sB[72 + oe + 8], 0.f);
        ffrow[p][oe + 16] = fmaxf(A2[0]+A2[1]+A2[2]+A2[3] + sB[72 + oe + 16], 0.f);
    }
    {
        const floatx4* fp = (const floatx4*)&ffrow[p][0];
        const floatx4* w0p = (const floatx4*)&sW2T[oe][0];
        const floatx4* w1p = (const floatx4*)&sW2T[oe + 8][0];
        const floatx4* w2p = (const floatx4*)&sW2T[oe + 16][0];
        floatx4 A0 = {0.f, 0.f, 0.f, 0.f}, A1 = A0, A2 = A0;
#pragma unroll
        for (int ii = 0; ii < 6; ii++) {
            floatx4 fv = fp[ii];
            A0 += fv * w0p[ii];
            A1 += fv * w1p[ii];
            A2 += fv * w2p[ii];
        }
        out[n * 24 + oe]      = xrow[p][oe]      + A0[0]+A0[1]+A0[2]+A0[3] + sB[96 + oe];
        out[n * 24 + oe + 8]  = xrow[p][oe + 8]  + A1[0]+A1[1]+A1[2]+A1[3] + sB[96 + oe + 8];
        out[n * 24 + oe + 16] = xrow[p][oe + 16] + A2[0]+A2[1]+A2[2]+A2[3] + sB[96 + oe + 16];
    }
}

extern "C" void kernel_launch(void* const* d_in, const int* in_sizes, int n_in,
                              void* d_out, int out_size, void* d_ws, size_t ws_size,
                              hipStream_t stream) {
    const float* x      = (const float*)d_in[0];
    const float* coords = (const float*)d_in[1];
    const float* n1g    = (const float*)d_in[2];
    const float* n1b    = (const float*)d_in[3];
    const float* Wq     = (const float*)d_in[4];
    const float* Wk     = (const float*)d_in[5];
    const float* Wv     = (const float*)d_in[6];
    const float* wrpe   = (const float*)d_in[7];
    const float* Wo     = (const float*)d_in[8];
    const float* bo     = (const float*)d_in[9];
    const float* n2g    = (const float*)d_in[10];
    const float* n2b    = (const float*)d_in[11];
    const float* W1     = (const float*)d_in[12];
    const float* b1     = (const float*)d_in[13];
    const float* W2     = (const float*)d_in[14];
    const float* b2     = (const float*)d_in[15];
    const float* alphas = (const float*)d_in[16];

    char* ws = (char*)d_ws;
    size_t off = 0;
    auto alloc = [&](size_t bytes) -> void* {
        void* p = ws + off;
        off = (off + bytes + 255) & ~(size_t)255;
        return p;
    };
    double* w64   = (double*)alloc(256);
    double* cqp   = (double*)alloc(256);
    double* Aq    = (double*)alloc(24 * NRH * 8);
    double* Ak    = (double*)alloc(24 * NRH * 8);
    double* ct    = (double*)alloc(NRH * 4 * 8);
    float*  xnf   = (float*)alloc((size_t)NPT * 24 * 4);
    ushort* qhatB = (ushort*)alloc((size_t)NH * NPT * 32 * 2);
    ushort* khatB = (ushort*)alloc((size_t)NH * NPT * 32 * 2);
    ushort* varrB = (ushort*)alloc((size_t)NH * NPT * 32 * 2);
    u64*    keys  = (u64*)alloc((size_t)NSEG * NPT * 8);
    ushort* ozB   = (ushort*)alloc((size_t)NHASH * NH * NPT * 32 * 2);
    if (off > ws_size) return;

    k0b<<<1, 256, 0, stream>>>(wrpe, Wq, Wk, alphas, w64, cqp, Aq, Ak, ct);
    k2s<<<NPT / 64, 512, 0, stream>>>(x, n1g, n1b, coords, Aq, Ak, ct, w64, keys, xnf);
    k2p_sort<<<192 + NPT / K2P_PTS, 1024, 0, stream>>>(keys, xnf, Wq, Wk, Wv, coords,
                                                       w64, cqp, qhatB, khatB, varrB);
    sort_tail1_fused<<<192, 1024, 0, stream>>>(keys);
    k3_attn<<<256 * 8 * 3, 256, 0, stream>>>(keys, qhatB, khatB, varrB, ozB);
    k4_final<<<NPT / K4PTS, 256, 0, stream>>>(ozB, x, Wo, bo, n2g, n2b,
                                              W1, b1, W2, b2, (float*)d_out);
}

// Round 11
// 276.891 us; speedup vs baseline: 1.0556x; 1.0265x over previous
//
#include <hip/hip_runtime.h>
#include <math.h>

#define NPT 32768
#define NH 8
#define HD 24
#define EDIM 28
#define NHASH 3
#define NSEG 48
#define NRH 24   // N_HASHES * NUM_HEADS = 24 alpha rows

typedef unsigned long long u64;
typedef unsigned short ushort;
typedef __attribute__((__vector_size__(8 * sizeof(short)))) short bf16x8;
typedef __attribute__((__vector_size__(4 * sizeof(float)))) float floatx4;
typedef __attribute__((__vector_size__(4 * sizeof(unsigned int)))) unsigned int uint32x4;

__device__ __forceinline__ ushort f2bf(float f) {
    unsigned u = __float_as_uint(f);
    unsigned r = u + 0x7FFF + ((u >> 16) & 1);
    return (ushort)(r >> 16);
}
__device__ __forceinline__ float us2f(ushort u) {
    return __uint_as_float(((unsigned)u) << 16);
}

// ---------------- K0b: RPE weights + folded score matrices (fp64) ----------------
__global__ __launch_bounds__(256) void k0b(
    const float* __restrict__ wrpe, const float* __restrict__ Wq,
    const float* __restrict__ Wk, const float* __restrict__ alphas,
    double* __restrict__ w64, double* __restrict__ cqp64,
    double* __restrict__ Aq, double* __restrict__ Ak, double* __restrict__ ct) {
    __shared__ double sw[16], sc[16];
    int t = threadIdx.x;
    if (t < 16) {
        int h = t >> 1, c = t & 1;
        double s = 0.0;
        for (int i = 0; i < 24; i++)
            for (int j = 0; j < 8; j++)
                s += (double)wrpe[(h * 24 + i) * 16 + c * 8 + j];
        double m = s / 192.0;
        sw[t] = m * m;
        sc[t] = sqrt(2.0) * fabs(m);
        w64[t] = sw[t];
        cqp64[t] = sc[t];
    }
    __syncthreads();
    const double QSCALE = 1.0 / sqrt(24.0);
    for (int idx = t; idx < 24 * NRH; idx += 256) {
        int i = idx / NRH, rh = idx % NRH;
        int h = rh & 7;
        double aq = 0.0, ak = 0.0;
        for (int e = 0; e < 24; e++) {
            double al = (double)alphas[rh * 28 + e];
            aq += (double)Wq[i * 192 + h * 24 + e] * al;
            ak += (double)Wk[i * 192 + h * 24 + e] * al;
        }
        Aq[idx] = aq * QSCALE;
        Ak[idx] = ak;
    }
    if (t < NRH) {
        int h = t & 7;
        ct[t * 4 + 0] = (double)alphas[t * 28 + 24] * sc[h * 2 + 0];
        ct[t * 4 + 1] = (double)alphas[t * 28 + 25] * sc[h * 2 + 1];
        ct[t * 4 + 2] = (double)alphas[t * 28 + 26];
        ct[t * 4 + 3] = (double)alphas[t * 28 + 27];
    }
}

// ---------------- K2s: fused fp64 LN + hash scores + xnf emit ----------------
__global__ __launch_bounds__(512) void k2s(
    const float* __restrict__ x, const float* __restrict__ n1g,
    const float* __restrict__ n1b, const float* __restrict__ coords,
    const double* __restrict__ Aq, const double* __restrict__ Ak,
    const double* __restrict__ ct, const double* __restrict__ w64,
    u64* __restrict__ keys, float* __restrict__ xnf) {
    __shared__ double sA[2][24][NRH];
    __shared__ double sCt[NRH][4];
    __shared__ double sW64[16];
    __shared__ double sGB[48];
    __shared__ double sXn[8][24];
    int t = threadIdx.x;
    for (int i = t; i < 24 * NRH; i += 512) sA[0][i / NRH][i % NRH] = Aq[i];
    for (int i = t; i < 24 * NRH; i += 512) sA[1][i / NRH][i % NRH] = Ak[i];
    for (int i = t; i < NRH * 4; i += 512) sCt[i / 4][i % 4] = ct[i];
    if (t < 16) sW64[t] = w64[t];
    if (t < 24) { sGB[t] = (double)n1g[t]; sGB[24 + t] = (double)n1b[t]; }
    __syncthreads();
    int wv = t >> 6, l = t & 63;
    for (int g = 0; g < 8; g++) {
        int n = blockIdx.x * 64 + g * 8 + wv;
        double xv = (l < 24) ? (double)x[(u64)n * 24 + l] : 0.0;
        double s = xv;
        s += __shfl_xor(s, 1); s += __shfl_xor(s, 2); s += __shfl_xor(s, 4);
        s += __shfl_xor(s, 8); s += __shfl_xor(s, 16);
        double mu = s / 24.0;
        double d = (l < 24) ? (xv - mu) : 0.0;
        double v2 = d * d;
        v2 += __shfl_xor(v2, 1); v2 += __shfl_xor(v2, 2); v2 += __shfl_xor(v2, 4);
        v2 += __shfl_xor(v2, 8); v2 += __shfl_xor(v2, 16);
        double rstd = 1.0 / sqrt(v2 / 24.0 + 1e-5);
        if (l < 24) {
            double xn = d * rstd * sGB[l] + sGB[24 + l];
            sXn[wv][l] = xn;
            xnf[(u64)n * 24 + l] = (float)xn;
        }
        // no barrier: sXn[wv] written and read by the same wave only
        double p0 = (double)coords[(u64)n * 3 + 1];
        double p1 = (double)coords[(u64)n * 3 + 2];
        if (l < 2 * NRH) {
            int qk = l / NRH, rh = l % NRH;
            int h = rh & 7;
            double sqn = sW64[2 * h] * p0 * p0 + sW64[2 * h + 1] * p1 * p1;
            double acc = sCt[rh][0] * p0 + sCt[rh][1] * p1;
            acc += qk ? (sCt[rh][2] - sqn * sCt[rh][3]) : (sCt[rh][3] - sqn * sCt[rh][2]);
            for (int i = 0; i < 24; i++) acc += sXn[wv][i] * sA[qk][i][rh];
            u64 u = (u64)__double_as_longlong(acc);
            if (u >> 63) u = ~u; else u |= 0x8000000000000000ULL;
            u64 key = (u & ~(u64)32767) | (u64)n;
            keys[(u64)l * NPT + n] = key;  // segment = qk*24 + rh = l
        }
    }
}

// ---------------- Bitonic sort helpers ----------------
__device__ __forceinline__ u64 shflx64(u64 v, int d) {
    int lo = __shfl_xor((int)(unsigned)v, d);
    int hi = __shfl_xor((int)(unsigned)(v >> 32), d);
    return ((u64)(unsigned)hi << 32) | (unsigned)lo;
}
__device__ __forceinline__ void cswap(u64& a, u64& b, bool up) {
    if ((a > b) == up) { u64 tmp = a; a = b; b = tmp; }
}
__device__ __forceinline__ u64* sslot(u64* s, int i) {
    int a = i << 3;
    a ^= ((a >> 9) & 7) << 4;
    return (u64*)((char*)s + a);
}
__device__ __forceinline__ void reg_passes(u64 e[8], int ib, int K, int jmax) {
    for (int j = jmax; j >= 1; j >>= 1) {
#pragma unroll
        for (int k = 0; k < 8; k++)
            if ((k & j) == 0) cswap(e[k], e[k | j], ((ib + k) & K) == 0);
    }
}
__device__ __forceinline__ void shfl_passes(u64 e[8], int t, int segoff, int K, int jhi, int jlo) {
    for (int j = jhi; j >= jlo; j >>= 1) {
        int d = j >> 3;
        bool lower = (t & d) == 0;
        bool up = ((segoff + ((t & ~d) << 3)) & K) == 0;
        bool keepmin = (lower == up);
#pragma unroll
        for (int k = 0; k < 8; k++) {
            u64 o = shflx64(e[k], d);
            bool ownsm = e[k] < o;
            e[k] = (ownsm == keepmin) ? e[k] : o;
        }
    }
}

// ---------------- Fused K2p + sort_local_full ----------------
// blockIdx < 192: full bitonic sort of one 8192-key chunk (unchanged logic).
// blockIdx >= 192: k2p projections for 32 points.
// __launch_bounds__(1024, 4): VGPR cap 128/wave -> k2p path's wc[24] stays
// in registers (round 10: this + corank-kernel deletion was worth ~21 us).
#define K2P_PTS 32
#define INVLN2F 1.4426950408889634f
__global__ __launch_bounds__(1024, 4) void k2p_sort(
    u64* keys,
    const float* __restrict__ xnf,
    const float* __restrict__ Wq, const float* __restrict__ Wk,
    const float* __restrict__ Wv, const float* __restrict__ coords,
    const double* __restrict__ w64, const double* __restrict__ cqp64,
    ushort* __restrict__ qhatB, ushort* __restrict__ khatB, ushort* __restrict__ varrB) {
    __shared__ __align__(16) char smem[65536];
    int t = threadIdx.x;
    if (blockIdx.x < 192) {
        // ---------- sort_local_full path ----------
        u64* s = (u64*)smem;
        u64 gbase = (u64)blockIdx.x * 8192;
        int segoff = (int)(gbase & 32767);
        int ib = segoff + t * 8;
        u64 e[8];
#pragma unroll
        for (int k = 0; k < 8; k++) e[k] = keys[gbase + t * 8 + k];
        reg_passes(e, ib, 2, 1);
        reg_passes(e, ib, 4, 2);
        reg_passes(e, ib, 8, 4);
        for (int K = 16; K <= 512; K <<= 1) {
            shfl_passes(e, t, segoff, K, K >> 1, 8);
            reg_passes(e, ib, K, 4);
        }
#pragma unroll
        for (int k = 0; k < 8; k++) *sslot(s, t * 8 + k) = e[k];
        __syncthreads();
        for (int K = 1024; K <= 8192; K <<= 1) {
            for (int j = K >> 1; j >= 512; j >>= 1) {
                for (int p = t; p < 4096; p += 1024) {
                    int i = ((p & ~(j - 1)) << 1) | (p & (j - 1));
                    int i2 = i | j;
                    bool up = (((segoff + i) & K) == 0);
                    u64 a = *sslot(s, i), b = *sslot(s, i2);
                    if ((a > b) == up) { *sslot(s, i) = b; *sslot(s, i2) = a; }
                }
                __syncthreads();
            }
#pragma unroll
            for (int k = 0; k < 8; k++) e[k] = *sslot(s, t * 8 + k);
            shfl_passes(e, t, segoff, K, 256, 8);
            reg_passes(e, ib, K, 4);
            if (K < 8192) {
#pragma unroll
                for (int k = 0; k < 8; k++) *sslot(s, t * 8 + k) = e[k];
                __syncthreads();
            } else {
#pragma unroll
                for (int k = 0; k < 8; k++) keys[gbase + t * 8 + k] = e[k];
            }
        }
    } else {
        // ---------- k2p path ----------
        ushort* sT = (ushort*)smem;   // [arr][h][pt][e] 49152 B
        int n0 = (blockIdx.x - 192) * K2P_PTS;
        if (t < 576) {
            int m = t / 192, jj = t % 192;
            const float* W = (m == 0) ? Wq : ((m == 1) ? Wk : Wv);
            float wc[24];
#pragma unroll
            for (int i = 0; i < 24; i++) wc[i] = W[i * 192 + jj];
            const float scale = (m == 0) ? (float)(1.4426950408889634 / sqrt(24.0)) : 1.0f;
            int h = jj / 24, e = jj % 24;
            ushort* sbase = sT + ((m * 8 + h) * K2P_PTS) * 32 + e;
            for (int p = 0; p < K2P_PTS; p++) {
                int n = n0 + p;
                const float* xr = xnf + (u64)n * 24;   // wave-uniform -> s_load
                float acc = 0.f;
#pragma unroll
                for (int i = 0; i < 24; i++) acc += xr[i] * wc[i];
                sbase[p * 32] = f2bf(acc * scale);
            }
        } else if (t < 640) {
            int l = t - 576;
            int h2 = l >> 3, e2 = 24 + (l & 7);
            double c0 = cqp64[h2 * 2], c1 = cqp64[h2 * 2 + 1];
            double wa = w64[h2 * 2], wb = w64[h2 * 2 + 1];
            ushort* qb = sT + ((0 * 8 + h2) * K2P_PTS) * 32 + e2;
            ushort* kb = sT + ((1 * 8 + h2) * K2P_PTS) * 32 + e2;
            ushort* vb = sT + ((2 * 8 + h2) * K2P_PTS) * 32 + e2;
            for (int p = 0; p < K2P_PTS; p++) {
                int n = n0 + p;
                double p0 = (double)coords[(u64)n * 3 + 1];
                double p1 = (double)coords[(u64)n * 3 + 2];
                float qv, kv;
                if (e2 < 26) {
                    int c = e2 - 24;
                    float qp = (float)((c ? c1 : c0) * (c ? p1 : p0));
                    qv = qp; kv = qp;
                } else if (e2 < 28) {
                    double sqn = wa * p0 * p0 + wb * p1 * p1;
                    if (e2 == 26) { qv = (float)(-sqn); kv = 1.0f; }
                    else          { qv = 1.0f; kv = (float)(-sqn); }
                } else {
                    qv = 0.0f; kv = 0.0f;
                }
                qb[p * 32] = f2bf(qv * INVLN2F);   // q-side 1/ln2 prescale
                kb[p * 32] = f2bf(kv);
                vb[p * 32] = 0;   // init pad cols of varr slab (copied out; not read)
            }
        }
        __syncthreads();
        // coalesced copy-out: 24 slabs x 128 16B-chunks = 3072.
        for (int c = t; c < 3 * 8 * K2P_PTS * 4; c += 1024) {
            int arrh = c >> 7, off = c & 127;
            int arr = arrh >> 3, hh = arrh & 7;
            uint32x4 v = *(const uint32x4*)(sT + arrh * (K2P_PTS * 32) + off * 8);
            ushort* op = (arr == 0) ? qhatB : ((arr == 1) ? khatB : varrB);
            *(uint32x4*)(op + (u64)hh * NPT * 32 + (u64)n0 * 32 + off * 8) = v;
        }
    }
}

// tail1 fused with the K=16384 j=8192 global pass: load own chunk + partner,
// keep min/max per element (keepmin for chunk-in-segment 0,3; max for 1,2),
// then run the K=16384 merge j=4096..1 (full sort of the 8192-chunk's role).
// After this kernel: segment first 16384 fully ASCENDING, second 16384 DESCENDING.
__global__ __launch_bounds__(1024) void sort_tail1_fused(u64* keys) {
    __shared__ u64 s[8192];
    int t = threadIdx.x;
    u64 gbase = (u64)blockIdx.x * 8192;
    u64 pbase = gbase ^ 8192ULL;          // partner chunk at distance j=8192
    int ci = (int)((gbase >> 13) & 3);    // chunk index within 32768-segment
    bool keepmin = (ci == 0) || (ci == 3);
    int segoff = (int)(gbase & 32767);
    int ib = segoff + t * 8;
    for (int i = t; i < 8192; i += 1024) {
        u64 a = keys[gbase + i];
        u64 b = keys[pbase + i];
        u64 mn = a < b ? a : b;
        u64 mx = a < b ? b : a;
        *sslot(s, i) = keepmin ? mn : mx;
    }
    __syncthreads();
    const int K = 16384;
    for (int j = 4096; j >= 512; j >>= 1) {
        for (int p = t; p < 4096; p += 1024) {
            int i = ((p & ~(j - 1)) << 1) | (p & (j - 1));
            int i2 = i | j;
            bool up = (((segoff + i) & K) == 0);
            u64 a = *sslot(s, i), b = *sslot(s, i2);
            if ((a > b) == up) { *sslot(s, i) = b; *sslot(s, i2) = a; }
        }
        __syncthreads();
    }
    u64 e[8];
#pragma unroll
    for (int k = 0; k < 8; k++) e[k] = *sslot(s, t * 8 + k);
    shfl_passes(e, t, segoff, K, 256, 8);
    reg_passes(e, ib, K, 4);
#pragma unroll
    for (int k = 0; k < 8; k++) keys[gbase + t * 8 + k] = e[k];
}

// ---------------- co-rank table ----------------
// Segment after tail1 = run A (16384 asc) ++ run B (16384 desc).
// corank(r): unique a with A[a-1] < B'[r-a] and B'[r-a-1] < A[a]
// (B'[i] = B[16383-i] ascending; keys distinct since low 15 bits = index).
__device__ __forceinline__ int corank(int r, const u64* __restrict__ A,
                                      const u64* __restrict__ B) {
    int lo = r - 16384; if (lo < 0) lo = 0;
    int hi = r < 16384 ? r : 16384;
    while (lo < hi) {
        int a = (lo + hi + 1) >> 1;          // a >= 1 in-loop
        int b = r - a;                        // 0 <= b < 16384 in-loop
        u64 Bv = B[16383 - b];                // B'[b]
        if (A[a - 1] < Bv) lo = a; else hi = a - 1;
    }
    return lo;
}
// Precompute all 48 x 257 boundary co-ranks (one search per thread, fully
// latency-parallel) so k3's prologue is 4 table loads instead of 4 serialized
// binary searches (round 10: in-block searches cost k3 +13.5 us).
__global__ __launch_bounds__(320) void corank_pre(const u64* __restrict__ keys,
                                                  int* __restrict__ cor) {
    int seg = blockIdx.x;
    int g = threadIdx.x;
    if (g > 256) return;
    const u64* A = keys + (u64)seg * NPT;
    const u64* B = A + 16384;
    cor[seg * 257 + g] = corank(g * 128, A, B);
}

// ---------------- K3: block attention via bf16 MFMA ----------------
// v10: co-rank boundaries read from precomputed table (4 loads); slice
// gathers from the two sorted runs. Rest = round-5 passing v2 structure +
// exp2f softmax.
__global__ __launch_bounds__(256, 4) void k3_attn(
    const u64* __restrict__ keys, const int* __restrict__ cor,
    const ushort* __restrict__ qhatB,
    const ushort* __restrict__ khatB, const ushort* __restrict__ varrB,
    ushort* __restrict__ ozB) {
    int rh3 = blockIdx.x % 24;
    int b = blockIdx.x / 24;
    int h = rh3 & 7, r = rh3 >> 3;
    __shared__ __align__(16) char smem[6144 + 32768 + 512 + 16];
    char* sVt = smem;                       // 24 rows x 256 B (phi-permuted, swizzled)
    char* sP  = smem + 6144;                // 128 rows x 256 B (phi-permuted, swizzled)
    ushort* qidx = (ushort*)(smem + 6144 + 32768);
    ushort* kidx = qidx + 128;
    int* sh = (int*)(smem + 6144 + 32768 + 512);
    int t = threadIdx.x;
    int segQ = r * 8 + h, segK = 24 + r * 8 + h;
    int r0 = b * 128;
    const u64* AQ = keys + (u64)segQ * NPT;
    const u64* BQ = AQ + 16384;
    const u64* AK = keys + (u64)segK * NPT;
    const u64* BK = AK + 16384;
    if (t < 4) {
        int segsel = (t < 2) ? segQ : segK;
        sh[t] = cor[segsel * 257 + b + (t & 1)];
    }
    __syncthreads();
    if (t < 128) {
        int aLo = sh[0], na = sh[1] - aLo, bLo = r0 - aLo;
        u64 v = (t < na) ? AQ[aLo + t] : BQ[16383 - (bLo + (t - na))];
        qidx[t] = (ushort)(v & 32767ULL);
    } else {
        int i = t - 128;
        int aLo = sh[2], na = sh[3] - aLo, bLo = r0 - aLo;
        u64 v = (i < na) ? AK[aLo + i] : BK[16383 - (bLo + (i - na))];
        kidx[i] = (ushort)(v & 32767ULL);
    }
    __syncthreads();

    int wave = t >> 6, L = t & 63;
    int quad = L >> 4, n16 = L & 15;

    const bf16x8* Qg = (const bf16x8*)(qhatB + (u64)h * NPT * 32);
    const bf16x8* Kg = (const bf16x8*)(khatB + (u64)h * NPT * 32);
    bf16x8 afr[2];
#pragma unroll
    for (int rtg = 0; rtg < 2; rtg++) {
        int qi = qidx[wave * 32 + rtg * 16 + n16];
        afr[rtg] = Qg[(u64)qi * 4 + quad];
    }
    bf16x8 bfr[8];
#pragma unroll
    for (int ct = 0; ct < 8; ct++) {
        int ki = kidx[ct * 16 + n16];
        bfr[ct] = Kg[(u64)ki * 4 + quad];
    }
    // stage V^T into phi-permuted + swizzled layout: key t -> byte col
    // phi(t)*2 = ((t&15)<<4)|((t>>4)<<1); per-row XOR (e&7)<<4.
    if (t < 128) {
        int ki = kidx[t];
        const bf16x8* vr = (const bf16x8*)(varrB + ((u64)h * NPT + ki) * 32);
        bf16x8 v0 = vr[0], v1 = vr[1], v2 = vr[2];
        int colb = ((t & 15) << 4) | ((t >> 4) << 1);
#pragma unroll
        for (int e = 0; e < 8; e++) {
            int e0 = e, e1 = 8 + e, e2 = 16 + e;
            *(short*)(sVt + e0 * 256 + (colb ^ ((e0 & 7) << 4))) = v0[e];
            *(short*)(sVt + e1 * 256 + (colb ^ ((e1 & 7) << 4))) = v1[e];
            *(short*)(sVt + e2 * 256 + (colb ^ ((e2 & 7) << 4))) = v2[e];
        }
    }
    __syncthreads();

    floatx4 acc[2][8];
#pragma unroll
    for (int rtg = 0; rtg < 2; rtg++)
#pragma unroll
        for (int ct = 0; ct < 8; ct++)
            acc[rtg][ct] = (floatx4){0.f, 0.f, 0.f, 0.f};
#pragma unroll
    for (int ct = 0; ct < 8; ct++) {
#pragma unroll
        for (int rtg = 0; rtg < 2; rtg++)
            acc[rtg][ct] = __builtin_amdgcn_mfma_f32_16x16x32_bf16(afr[rtg], bfr[ct], acc[rtg][ct], 0, 0, 0);
    }

    // Softmax (scores in log2 units; exp2f = native v_exp_f32).
    float mrow[2][4], srow[2][4];
#pragma unroll
    for (int rtg = 0; rtg < 2; rtg++) {
#pragma unroll
        for (int rg = 0; rg < 4; rg++) {
            float m = acc[rtg][0][rg];
#pragma unroll
            for (int ct = 1; ct < 8; ct++) m = fmaxf(m, acc[rtg][ct][rg]);
            m = fmaxf(m, __shfl_xor(m, 1));
            m = fmaxf(m, __shfl_xor(m, 2));
            m = fmaxf(m, __shfl_xor(m, 4));
            m = fmaxf(m, __shfl_xor(m, 8));
            mrow[rtg][rg] = m;
            float p[8];
            float s = 0.0f;
#pragma unroll
            for (int ct = 0; ct < 8; ct++) {
                p[ct] = exp2f(acc[rtg][ct][rg] - m);
                s += p[ct];
            }
            s += __shfl_xor(s, 1);
            s += __shfl_xor(s, 2);
            s += __shfl_xor(s, 4);
            s += __shfl_xor(s, 8);
            srow[rtg][rg] = s;
            unsigned w0, w1, w2, w3;
            asm("v_cvt_pk_bf16_f32 %0, %1, %2" : "=v"(w0) : "v"(p[0]), "v"(p[1]));
            asm("v_cvt_pk_bf16_f32 %0, %1, %2" : "=v"(w1) : "v"(p[2]), "v"(p[3]));
            asm("v_cvt_pk_bf16_f32 %0, %1, %2" : "=v"(w2) : "v"(p[4]), "v"(p[5]));
            asm("v_cvt_pk_bf16_f32 %0, %1, %2" : "=v"(w3) : "v"(p[6]), "v"(p[7]));
            int row = wave * 32 + rtg * 16 + quad * 4 + rg;
            uint32x4 pk = {w0, w1, w2, w3};
            *(uint32x4*)(sP + row * 256 + (((n16 << 4)) ^ ((row & 7) << 4))) = pk;
        }
    }
    // sP written and read by the same wave only -> no barrier needed.

    floatx4 occ[2][2];
#pragma unroll
    for (int rtg = 0; rtg < 2; rtg++)
#pragma unroll
        for (int ct2 = 0; ct2 < 2; ct2++)
            occ[rtg][ct2] = (floatx4){0.f, 0.f, 0.f, 0.f};
#pragma unroll
    for (int ks = 0; ks < 4; ks++) {
        int kb = ks * 64 + quad * 16;   // byte offset of this lane's 8 phys cols
        bf16x8 bv[2], av[2];
#pragma unroll
        for (int ct2 = 0; ct2 < 2; ct2++) {
            int e = ct2 * 16 + n16;
            int ec = (e < 24) ? e : 0;  // cols 24..31 discarded; clamp keeps reads in sVt
            bv[ct2] = *(const bf16x8*)(sVt + ec * 256 + (kb ^ ((ec & 7) << 4)));
        }
#pragma unroll
        for (int rtg = 0; rtg < 2; rtg++) {
            int rowA = wave * 32 + rtg * 16 + n16;
            av[rtg] = *(const bf16x8*)(sP + rowA * 256 + (kb ^ ((rowA & 7) << 4)));
        }
#pragma unroll
        for (int rtg = 0; rtg < 2; rtg++)
#pragma unroll
            for (int ct2 = 0; ct2 < 2; ct2++)
                occ[rtg][ct2] = __builtin_amdgcn_mfma_f32_16x16x32_bf16(av[rtg], bv[ct2], occ[rtg][ct2], 0, 0, 0);
    }

    const float LN2F = 0.6931471805599453f;
#pragma unroll
    for (int rtg = 0; rtg < 2; rtg++) {
#pragma unroll
        for (int rg = 0; rg < 4; rg++) {
            int row = wave * 32 + rtg * 16 + quad * 4 + rg;
            int oi = qidx[row];
            float inv = 1.0f / srow[rtg][rg];
            ushort* orow = ozB + ((u64)segQ * NPT + oi) * 32;
#pragma unroll
            for (int ct2 = 0; ct2 < 2; ct2++) {
                int col = ct2 * 16 + n16;
                if (col < 24) orow[col] = f2bf(occ[rtg][ct2][rg] * inv);
            }
            if (n16 == 0)
                *(float*)(orow + 24) = mrow[rtg][rg] * LN2F + __logf(srow[rtg][rg]);
        }
    }
}

// ---------------- K4: hash combine + Wo + residual + LN2 + FFN (fp32, 32 pts/block) ----------------
#define K4PTS 32
#define AT_STR 196   // floats; 16B-aligned rows
#define W_STR 28     // transposed small-matrix row stride (16B-aligned)
__global__ __launch_bounds__(256) void k4_final(
    const ushort* __restrict__ ozB,
    const float* __restrict__ x,
    const float* __restrict__ Wo, const float* __restrict__ bo,
    const float* __restrict__ g2, const float* __restrict__ b2,
    const float* __restrict__ W1, const float* __restrict__ b1f,
    const float* __restrict__ W2, const float* __restrict__ b2f,
    float* __restrict__ out) {
    __shared__ __align__(16) float sWoT[24][AT_STR];
    __shared__ __align__(16) float sW1T[24][W_STR], sW2T[24][W_STR];
    __shared__ float sB[5 * 24];
    __shared__ __align__(16) float attn[K4PTS][AT_STR];
    __shared__ float xrow[K4PTS][25];
    __shared__ __align__(16) float h2row[K4PTS][W_STR];
    __shared__ __align__(16) float ffrow[K4PTS][W_STR];
    int t = threadIdx.x;
    int base = blockIdx.x * K4PTS;
    for (int i = t; i < 4608; i += 256) sWoT[i % 24][i / 24] = Wo[i];
    for (int i = t; i < 576; i += 256) {
        sW1T[i % 24][i / 24] = W1[i];   // sW1T[out][in]
        sW2T[i % 24][i / 24] = W2[i];
    }
    if (t < 24) {
        sB[t] = bo[t]; sB[24 + t] = g2[t]; sB[48 + t] = b2[t];
        sB[72 + t] = b1f[t]; sB[96 + t] = b2f[t];
    }
    // zero the pad columns so float4 reads over 24..27 are benign
    if (t < K4PTS * 4) {
        int p = t >> 2, c = 24 + (t & 3);
        h2row[p][c] = 0.f; ffrow[p][c] = 0.f;
    }
    if (t < 24 * 4) {
        int rr = t >> 2, c = 24 + (t & 3);
        sW1T[rr][c] = 0.f; sW2T[rr][c] = 0.f;
    }
    {
        int p = t >> 3, h = t & 7;
        int n = base + p;
        const ushort* r0 = ozB + ((u64)(0 * 8 + h) * NPT + n) * 32;
        const ushort* r1 = ozB + ((u64)(1 * 8 + h) * NPT + n) * 32;
        const ushort* r2 = ozB + ((u64)(2 * 8 + h) * NPT + n) * 32;
        float z0 = *(const float*)(r0 + 24);
        float z1 = *(const float*)(r1 + 24);
        float z2 = *(const float*)(r2 + 24);
        float zm = fmaxf(z0, fmaxf(z1, z2));
        float e0 = __expf(z0 - zm), e1 = __expf(z1 - zm), e2 = __expf(z2 - zm);
        float inv = 1.0f / (e0 + e1 + e2);
        float w0 = e0 * inv, w1 = e1 * inv, w2 = e2 * inv;
#pragma unroll
        for (int e = 0; e < 24; e++)
            attn[p][h * 24 + e] = w0 * us2f(r0[e]) + w1 * us2f(r1[e]) + w2 * us2f(r2[e]);
    }
    __syncthreads();
    int p = t >> 3, oe = t & 7;
    int n = base + p;
    {
        const floatx4* ap = (const floatx4*)&attn[p][0];
        const floatx4* w0p = (const floatx4*)&sWoT[oe][0];
        const floatx4* w1p = (const floatx4*)&sWoT[oe + 8][0];
        const floatx4* w2p = (const floatx4*)&sWoT[oe + 16][0];
        floatx4 A0 = {0.f, 0.f, 0.f, 0.f}, A1 = A0, A2 = A0;
        for (int ii = 0; ii < 48; ii++) {
            floatx4 av = ap[ii];
            A0 += av * w0p[ii];
            A1 += av * w1p[ii];
            A2 += av * w2p[ii];
        }
        float a0 = A0[0] + A0[1] + A0[2] + A0[3];
        float a1 = A1[0] + A1[1] + A1[2] + A1[3];
        float a2 = A2[0] + A2[1] + A2[2] + A2[3];
        xrow[p][oe]      = x[n * 24 + oe]      + a0 + sB[oe];
        xrow[p][oe + 8]  = x[n * 24 + oe + 8]  + a1 + sB[oe + 8];
        xrow[p][oe + 16] = x[n * 24 + oe + 16] + a2 + sB[oe + 16];
    }
    float mu, rstd;
    {
        float s = xrow[p][oe] + xrow[p][oe + 8] + xrow[p][oe + 16];
        s += __shfl_xor(s, 1); s += __shfl_xor(s, 2); s += __shfl_xor(s, 4);
        mu = s / 24.0f;
        float v0 = xrow[p][oe] - mu, v1 = xrow[p][oe + 8] - mu, v2 = xrow[p][oe + 16] - mu;
        float v = v0 * v0 + v1 * v1 + v2 * v2;
        v += __shfl_xor(v, 1); v += __shfl_xor(v, 2); v += __shfl_xor(v, 4);
        rstd = 1.0f / sqrtf(v / 24.0f + 1e-5f);
    }
    h2row[p][oe]      = (xrow[p][oe] - mu)      * rstd * sB[24 + oe]      + sB[48 + oe];
    h2row[p][oe + 8]  = (xrow[p][oe + 8] - mu)  * rstd * sB[24 + oe + 8]  + sB[48 + oe + 8];
    h2row[p][oe + 16] = (xrow[p][oe + 16] - mu) * rstd * sB[24 + oe + 16] + sB[48 + oe + 16];
    {
        const floatx4* hp = (const floatx4*)&h2row[p][0];
        const floatx4* w0p = (const floatx4*)&sW1T[oe][0];
        const floatx4* w1p = (const floatx4*)&sW1T[oe + 8][0];
        const floatx4* w2p = (const floatx4*)&sW1T[oe + 16][0];
        floatx4 A0 = {0.f, 0.f, 0.f, 0.f}, A1 = A0, A2 = A0;
#pragma unroll
        for (int ii = 0; ii < 6; ii++) {
            floatx4 hv = hp[ii];
            A0 += hv * w0p[ii];
            A1 += hv * w1p[ii];
            A2 += hv * w2p[ii];
        }
        ffrow[p][oe]      = fmaxf(A0[0]+A0[1]+A0[2]+A0[3] + sB[72 + oe], 0.f);
        ffrow[p][oe + 8]  = fmaxf(A1[0]+A1[1]+A1[2]+A1[3] + sB[72 + oe + 8], 0.f);
        ffrow[p][oe + 16] = fmaxf(A2[0]+A2[1]+A2[2]+A2[3] + sB[72 + oe + 16], 0.f);
    }
    {
        const floatx4* fp = (const floatx4*)&ffrow[p][0];
        const floatx4* w0p = (const floatx4*)&sW2T[oe][0];
        const floatx4* w1p = (const floatx4*)&sW2T[oe + 8][0];
        const floatx4* w2p = (const floatx4*)&sW2T[oe + 16][0];
        floatx4 A0 = {0.f, 0.f, 0.f, 0.f}, A1 = A0, A2 = A0;
#pragma unroll
        for (int ii = 0; ii < 6; ii++) {
            floatx4 fv = fp[ii];
            A0 += fv * w0p[ii];
            A1 += fv * w1p[ii];
            A2 += fv * w2p[ii];
        }
        out[n * 24 + oe]      = xrow[p][oe]      + A0[0]+A0[1]+A0[2]+A0[3] + sB[96 + oe];
        out[n * 24 + oe + 8]  = xrow[p][oe + 8]  + A1[0]+A1[1]+A1[2]+A1[3] + sB[96 + oe + 8];
        out[n * 24 + oe + 16] = xrow[p][oe + 16] + A2[0]+A2[1]+A2[2]+A2[3] + sB[96 + oe + 16];
    }
}

extern "C" void kernel_launch(void* const* d_in, const int* in_sizes, int n_in,
                              void* d_out, int out_size, void* d_ws, size_t ws_size,
                              hipStream_t stream) {
    const float* x      = (const float*)d_in[0];
    const float* coords = (const float*)d_in[1];
    const float* n1g    = (const float*)d_in[2];
    const float* n1b    = (const float*)d_in[3];
    const float* Wq     = (const float*)d_in[4];
    const float* Wk     = (const float*)d_in[5];
    const float* Wv     = (const float*)d_in[6];
    const float* wrpe   = (const float*)d_in[7];
    const float* Wo     = (const float*)d_in[8];
    const float* bo     = (const float*)d_in[9];
    const float* n2g    = (const float*)d_in[10];
    const float* n2b    = (const float*)d_in[11];
    const float* W1     = (const float*)d_in[12];
    const float* b1     = (const float*)d_in[13];
    const float* W2     = (const float*)d_in[14];
    const float* b2     = (const float*)d_in[15];
    const float* alphas = (const float*)d_in[16];

    char* ws = (char*)d_ws;
    size_t off = 0;
    auto alloc = [&](size_t bytes) -> void* {
        void* p = ws + off;
        off = (off + bytes + 255) & ~(size_t)255;
        return p;
    };
    double* w64   = (double*)alloc(256);
    double* cqp   = (double*)alloc(256);
    double* Aq    = (double*)alloc(24 * NRH * 8);
    double* Ak    = (double*)alloc(24 * NRH * 8);
    double* ct    = (double*)alloc(NRH * 4 * 8);
    float*  xnf   = (float*)alloc((size_t)NPT * 24 * 4);
    ushort* qhatB = (ushort*)alloc((size_t)NH * NPT * 32 * 2);
    ushort* khatB = (ushort*)alloc((size_t)NH * NPT * 32 * 2);
    ushort* varrB = (ushort*)alloc((size_t)NH * NPT * 32 * 2);
    u64*    keys  = (u64*)alloc((size_t)NSEG * NPT * 8);
    int*    cor   = (int*)alloc((size_t)NSEG * 257 * 4);
    ushort* ozB   = (ushort*)alloc((size_t)NHASH * NH * NPT * 32 * 2);
    if (off > ws_size) return;

    k0b<<<1, 256, 0, stream>>>(wrpe, Wq, Wk, alphas, w64, cqp, Aq, Ak, ct);
    k2s<<<NPT / 64, 512, 0, stream>>>(x, n1g, n1b, coords, Aq, Ak, ct, w64, keys, xnf);
    k2p_sort<<<192 + NPT / K2P_PTS, 1024, 0, stream>>>(keys, xnf, Wq, Wk, Wv, coords,
                                                       w64, cqp, qhatB, khatB, varrB);
    sort_tail1_fused<<<192, 1024, 0, stream>>>(keys);
    corank_pre<<<NSEG, 320, 0, stream>>>(keys, cor);
    k3_attn<<<256 * 8 * 3, 256, 0, stream>>>(keys, cor, qhatB, khatB, varrB, ozB);
    k4_final<<<NPT / K4PTS, 256, 0, stream>>>(ozB, x, Wo, bo, n2g, n2b,
                                              W1, b1, W2, b2, (float*)d_out);
}